// Round 1
// baseline (2353.485 us; speedup 1.0000x reference)
//
#include <hip/hip_runtime.h>

#define SEQ 512
#define DIM 1024
#define NH 16
#define HD 64
#define NREL 129
#define EROW 132
#define SCALE 0.125f

// ---------------- projection GEMM: C[8192x1024] = A[8192x1024] @ W[1024x1024]
__global__ __launch_bounds__(256) void proj_gemm(const float* __restrict__ A,
                                                 const float* __restrict__ W,
                                                 float* __restrict__ C) {
    __shared__ float As[16][132];  // [k][m], 128 rows + pad
    __shared__ float Bs[16][68];   // [k][n]
    const int t = threadIdx.x;
    const int bm = blockIdx.x & 63;   // 8192/128
    const int bn = blockIdx.x >> 6;   // 1024/64
    const int m0 = bm * 128, n0 = bn * 64;
    const int tm = t >> 4, tn = t & 15;
    const int lm = t >> 2;           // 0..63
    const int lk = (t & 3) * 4;      // 0,4,8,12
    const int wk = t >> 4;           // 0..15
    const int wn = (t & 15) * 4;

    float acc[8][4];
#pragma unroll
    for (int i = 0; i < 8; i++)
#pragma unroll
        for (int j = 0; j < 4; j++) acc[i][j] = 0.f;

    for (int k0 = 0; k0 < 1024; k0 += 16) {
        float4 a0 = *(const float4*)&A[(m0 + lm) * 1024 + k0 + lk];
        float4 a1 = *(const float4*)&A[(m0 + lm + 64) * 1024 + k0 + lk];
        float4 b0 = *(const float4*)&W[(k0 + wk) * 1024 + n0 + wn];
        As[lk + 0][lm] = a0.x; As[lk + 1][lm] = a0.y;
        As[lk + 2][lm] = a0.z; As[lk + 3][lm] = a0.w;
        As[lk + 0][lm + 64] = a1.x; As[lk + 1][lm + 64] = a1.y;
        As[lk + 2][lm + 64] = a1.z; As[lk + 3][lm + 64] = a1.w;
        *(float4*)&Bs[wk][wn] = b0;
        __syncthreads();
#pragma unroll
        for (int k = 0; k < 16; k++) {
            float4 av0 = *(const float4*)&As[k][tm * 8];
            float4 av1 = *(const float4*)&As[k][tm * 8 + 4];
            float4 b4  = *(const float4*)&Bs[k][tn * 4];
            float a[8] = {av0.x, av0.y, av0.z, av0.w, av1.x, av1.y, av1.z, av1.w};
            float bb[4] = {b4.x, b4.y, b4.z, b4.w};
#pragma unroll
            for (int i = 0; i < 8; i++)
#pragma unroll
                for (int j = 0; j < 4; j++) acc[i][j] += a[i] * bb[j];
        }
        __syncthreads();
    }
#pragma unroll
    for (int i = 0; i < 8; i++) {
        float4 o = make_float4(acc[i][0], acc[i][1], acc[i][2], acc[i][3]);
        *(float4*)&C[(m0 + tm * 8 + i) * 1024 + n0 + tn * 4] = o;
    }
}

// ---------------- ee[r] = dot(Eq[r], Ek[r])
__global__ void ee_k(const float* __restrict__ Eq, const float* __restrict__ Ek,
                     float* __restrict__ ee) {
    int r = threadIdx.x;
    if (r < NREL) {
        float s = 0.f;
        for (int d = 0; d < HD; d++) s += Eq[r * HD + d] * Ek[r * HD + d];
        ee[r] = s;
    }
}

// ---------------- qE[g][r] = Qrow(g)·Ek[r], kE[g][r] = Krow(g)·Eq[r]
// rows g index (b*S+s)*H+h ; Q viewed as (131072, 64)
__global__ __launch_bounds__(256) void qk_e(const float* __restrict__ Q,
                                            const float* __restrict__ K,
                                            const float* __restrict__ Eq,
                                            const float* __restrict__ Ek,
                                            float* __restrict__ qE,
                                            float* __restrict__ kE) {
    __shared__ float EkS[NREL][68];
    __shared__ float EqS[NREL][68];
    __shared__ float Qs[16][68];
    __shared__ float Ks[16][68];
    const int t = threadIdx.x;
    const int g0 = blockIdx.x * 16;

    for (int i = t; i < NREL * 16; i += 256) {
        int r = i >> 4, d4 = (i & 15) * 4;
        *(float4*)&EkS[r][d4] = *(const float4*)&Ek[r * HD + d4];
        *(float4*)&EqS[r][d4] = *(const float4*)&Eq[r * HD + d4];
    }
    {
        int l = t >> 4, d4 = (t & 15) * 4;
        *(float4*)&Qs[l][d4] = *(const float4*)&Q[(g0 + l) * HD + d4];
        *(float4*)&Ks[l][d4] = *(const float4*)&K[(g0 + l) * HD + d4];
    }
    __syncthreads();
    const int l = t >> 4, rr = t & 15;
#pragma unroll
    for (int j = 0; j < 9; j++) {
        int r = rr + 16 * j;
        if (r < NREL) {
            float aq = 0.f, ak = 0.f;
#pragma unroll
            for (int d = 0; d < HD; d += 4) {
                float4 q4 = *(const float4*)&Qs[l][d];
                float4 k4 = *(const float4*)&Ks[l][d];
                float4 e4 = *(const float4*)&EkS[r][d];
                float4 f4 = *(const float4*)&EqS[r][d];
                aq += q4.x * e4.x + q4.y * e4.y + q4.z * e4.z + q4.w * e4.w;
                ak += k4.x * f4.x + k4.y * f4.y + k4.z * f4.z + k4.w * f4.w;
            }
            qE[(g0 + l) * EROW + r] = aq;
            kE[(g0 + l) * EROW + r] = ak;
        }
    }
}

// ---------------- attention: one block = (b,h, 16 l-rows)
__global__ __launch_bounds__(256) void attn_k(const float* __restrict__ Q,
                                              const float* __restrict__ K,
                                              const float* __restrict__ V,
                                              const float* __restrict__ qE,
                                              const float* __restrict__ kE,
                                              const float* __restrict__ ee,
                                              const float* __restrict__ Ev,
                                              float* __restrict__ out) {
    __shared__ float Qs[16][68];
    __shared__ float Ks[64][68];
    __shared__ float lg[16][520];
    __shared__ float aR[16][132];
    const int t = threadIdx.x;
    const int bh = blockIdx.x >> 5;
    const int lt = blockIdx.x & 31;
    const int b = bh >> 4, h = bh & 15;
    const int l0 = lt * 16;
    const int l = t >> 4;
    const int d4 = (t & 15) * 4;
    const int mm = t & 15;

    {
        int gq = (b * SEQ + l0 + l) * NH + h;
        *(float4*)&Qs[l][d4] = *(const float4*)&Q[gq * HD + d4];
    }
    for (int i = t; i < 16 * 132; i += 256) (&aR[0][0])[i] = 0.f;

    // ---- pass 1: logits
    for (int mt = 0; mt < 8; mt++) {
        __syncthreads();
#pragma unroll
        for (int i = 0; i < 4; i++) {
            int mrow = (t >> 4) + i * 16;
            int gk = (b * SEQ + mt * 64 + mrow) * NH + h;
            *(float4*)&Ks[mrow][d4] = *(const float4*)&K[gk * HD + d4];
        }
        __syncthreads();
        float acc[4] = {0.f, 0.f, 0.f, 0.f};
        for (int d = 0; d < HD; d += 4) {
            float4 q4 = *(const float4*)&Qs[l][d];
#pragma unroll
            for (int jj = 0; jj < 4; jj++) {
                float4 k4 = *(const float4*)&Ks[mm + jj * 16][d];
                acc[jj] += q4.x * k4.x + q4.y * k4.y + q4.z * k4.z + q4.w * k4.w;
            }
        }
        const int qrow = ((b * SEQ + l0 + l) * NH + h) * EROW;
#pragma unroll
        for (int jj = 0; jj < 4; jj++) {
            int m = mt * 64 + mm + jj * 16;
            int dlt = (l0 + l) - m;
            int r = (dlt < -64 ? -64 : (dlt > 64 ? 64 : dlt)) + 64;
            int krow = ((b * SEQ + m) * NH + h) * EROW;
            float v = acc[jj] + qE[qrow + r] + kE[krow + r] + ee[r];
            lg[l][m] = v * SCALE;
        }
    }
    __syncthreads();

    // ---- pass 2: softmax + relative-bucket mass (wave per 4 rows)
    const int wv = t >> 6;
    const int lane = t & 63;
    for (int rw = 0; rw < 4; rw++) {
        int row = wv * 4 + rw;
        float p[8];
        float mx = -1e30f;
#pragma unroll
        for (int j = 0; j < 8; j++) { p[j] = lg[row][lane + 64 * j]; mx = fmaxf(mx, p[j]); }
        for (int off = 32; off; off >>= 1) mx = fmaxf(mx, __shfl_xor(mx, off));
        float s = 0.f;
#pragma unroll
        for (int j = 0; j < 8; j++) { p[j] = __expf(p[j] - mx); s += p[j]; }
        for (int off = 32; off; off >>= 1) s += __shfl_xor(s, off);
        float inv = 1.0f / s;
        float s0 = 0.f, s128 = 0.f;
#pragma unroll
        for (int j = 0; j < 8; j++) {
            float a = p[j] * inv;
            int m = lane + 64 * j;
            lg[row][m] = a;
            int dlt = (l0 + row) - m;
            if (dlt >= 64)       s128 += a;
            else if (dlt <= -64) s0 += a;
            else                 aR[row][dlt + 64] = a;
        }
        for (int off = 32; off; off >>= 1) {
            s0 += __shfl_xor(s0, off);
            s128 += __shfl_xor(s128, off);
        }
        if (lane == 0) { aR[row][0] = s0; aR[row][128] = s128; }
    }
    __syncthreads();

    // ---- pass 3: out = attn@V + attnR@Ev
    float o0 = 0.f, o1 = 0.f, o2 = 0.f, o3 = 0.f;
    for (int mt = 0; mt < 8; mt++) {
        __syncthreads();
#pragma unroll
        for (int i = 0; i < 4; i++) {
            int mrow = (t >> 4) + i * 16;
            int gv = (b * SEQ + mt * 64 + mrow) * NH + h;
            *(float4*)&Ks[mrow][d4] = *(const float4*)&V[gv * HD + d4];
        }
        __syncthreads();
        for (int mloc = 0; mloc < 64; mloc++) {
            float a = lg[l][mt * 64 + mloc];
            float4 v4 = *(const float4*)&Ks[mloc][d4];
            o0 += a * v4.x; o1 += a * v4.y; o2 += a * v4.z; o3 += a * v4.w;
        }
    }
    for (int r = 0; r < NREL; r++) {
        float a = aR[l][r];
        float4 e4 = *(const float4*)&Ev[r * HD + d4];
        o0 += a * e4.x; o1 += a * e4.y; o2 += a * e4.z; o3 += a * e4.w;
    }
    int go = (b * SEQ + l0 + l) * NH + h;
    *(float4*)&out[go * HD + d4] = make_float4(o0, o1, o2, o3);
}

extern "C" void kernel_launch(void* const* d_in, const int* in_sizes, int n_in,
                              void* d_out, int out_size, void* d_ws, size_t ws_size,
                              hipStream_t stream) {
    const float* x  = (const float*)d_in[0];
    const float* Wq = (const float*)d_in[1];
    const float* Wk = (const float*)d_in[2];
    const float* Wv = (const float*)d_in[3];
    const float* Eq = (const float*)d_in[4];
    const float* Ek = (const float*)d_in[5];
    const float* Ev = (const float*)d_in[6];
    float* out = (float*)d_out;
    char* ws = (char*)d_ws;

    float* Qm = (float*)(ws);                     // 33,554,432 B
    float* Km = (float*)(ws + 33554432ull);
    float* Vm = (float*)(ws + 67108864ull);
    float* qE = (float*)(ws + 100663296ull);      // 69,206,016 B
    float* kE = (float*)(ws + 169869312ull);
    float* ee = (float*)(ws + 239075328ull);      // 528 B

    proj_gemm<<<1024, 256, 0, stream>>>(x, Wq, Qm);
    proj_gemm<<<1024, 256, 0, stream>>>(x, Wk, Km);
    proj_gemm<<<1024, 256, 0, stream>>>(x, Wv, Vm);
    ee_k<<<1, 256, 0, stream>>>(Eq, Ek, ee);
    qk_e<<<8192, 256, 0, stream>>>(Qm, Km, Eq, Ek, qE, kE);
    attn_k<<<8192, 256, 0, stream>>>(Qm, Km, Vm, qE, kE, ee, Ev, out);
}

// Round 2
// 1349.490 us; speedup vs baseline: 1.7440x; 1.7440x over previous
//
#include <hip/hip_runtime.h>

#define SEQ 512
#define NH 16
#define HD 64
#define NREL 129
#define ER 136          // padded bf16 row stride (136*2 = 272 B, 16B-aligned)
#define SCALE 0.125f

typedef __attribute__((ext_vector_type(8))) short bf16x8;
typedef __attribute__((ext_vector_type(4))) float f32x4;

__device__ __forceinline__ unsigned short f2bf(float x) {
    unsigned u = __builtin_bit_cast(unsigned, x);
    u += 0x7FFFu + ((u >> 16) & 1u);
    return (unsigned short)(u >> 16);
}
__device__ __forceinline__ float bf2f(unsigned short s) {
    unsigned u = ((unsigned)s) << 16;
    return __builtin_bit_cast(float, u);
}

// ---------------- projection GEMM: C[8192x1024] = A[8192x1024] @ W[1024x1024]
__global__ __launch_bounds__(256) void proj_gemm(const float* __restrict__ A,
                                                 const float* __restrict__ W,
                                                 float* __restrict__ C) {
    __shared__ float As[16][132];
    __shared__ float Bs[16][68];
    const int t = threadIdx.x;
    const int bm = blockIdx.x & 63;
    const int bn = blockIdx.x >> 6;
    const int m0 = bm * 128, n0 = bn * 64;
    const int tm = t >> 4, tn = t & 15;
    const int lm = t >> 2;
    const int lk = (t & 3) * 4;
    const int wk = t >> 4;
    const int wn = (t & 15) * 4;

    float acc[8][4];
#pragma unroll
    for (int i = 0; i < 8; i++)
#pragma unroll
        for (int j = 0; j < 4; j++) acc[i][j] = 0.f;

    for (int k0 = 0; k0 < 1024; k0 += 16) {
        float4 a0 = *(const float4*)&A[(m0 + lm) * 1024 + k0 + lk];
        float4 a1 = *(const float4*)&A[(m0 + lm + 64) * 1024 + k0 + lk];
        float4 b0 = *(const float4*)&W[(k0 + wk) * 1024 + n0 + wn];
        As[lk + 0][lm] = a0.x; As[lk + 1][lm] = a0.y;
        As[lk + 2][lm] = a0.z; As[lk + 3][lm] = a0.w;
        As[lk + 0][lm + 64] = a1.x; As[lk + 1][lm + 64] = a1.y;
        As[lk + 2][lm + 64] = a1.z; As[lk + 3][lm + 64] = a1.w;
        *(float4*)&Bs[wk][wn] = b0;
        __syncthreads();
#pragma unroll
        for (int k = 0; k < 16; k++) {
            float4 av0 = *(const float4*)&As[k][tm * 8];
            float4 av1 = *(const float4*)&As[k][tm * 8 + 4];
            float4 b4  = *(const float4*)&Bs[k][tn * 4];
            float a[8] = {av0.x, av0.y, av0.z, av0.w, av1.x, av1.y, av1.z, av1.w};
            float bb[4] = {b4.x, b4.y, b4.z, b4.w};
#pragma unroll
            for (int i = 0; i < 8; i++)
#pragma unroll
                for (int j = 0; j < 4; j++) acc[i][j] += a[i] * bb[j];
        }
        __syncthreads();
    }
#pragma unroll
    for (int i = 0; i < 8; i++) {
        float4 o = make_float4(acc[i][0], acc[i][1], acc[i][2], acc[i][3]);
        *(float4*)&C[(m0 + tm * 8 + i) * 1024 + n0 + tn * 4] = o;
    }
}

// ---------------- ee[r] = dot(Eq[r], Ek[r])
__global__ void ee_k(const float* __restrict__ Eq, const float* __restrict__ Ek,
                     float* __restrict__ ee) {
    int r = threadIdx.x;
    if (r < NREL) {
        float s = 0.f;
        for (int d = 0; d < HD; d++) s += Eq[r * HD + d] * Ek[r * HD + d];
        ee[r] = s;
    }
}

// ---------------- qEe[g][r] = Qrow(g)·Ek[r] + ee[r], kEb[g][r] = Krow(g)·Eq[r]  (bf16)
__global__ __launch_bounds__(256) void qk_e(const float* __restrict__ Q,
                                            const float* __restrict__ K,
                                            const float* __restrict__ Eq,
                                            const float* __restrict__ Ek,
                                            const float* __restrict__ ee,
                                            unsigned short* __restrict__ qEe,
                                            unsigned short* __restrict__ kEb) {
    __shared__ float EkS[NREL][68];
    __shared__ float EqS[NREL][68];
    __shared__ float Qs[16][68];
    __shared__ float Ks[16][68];
    __shared__ float eeS[NREL];
    const int t = threadIdx.x;
    const int g0 = blockIdx.x * 16;

    for (int i = t; i < NREL * 16; i += 256) {
        int r = i >> 4, d4 = (i & 15) * 4;
        *(float4*)&EkS[r][d4] = *(const float4*)&Ek[r * HD + d4];
        *(float4*)&EqS[r][d4] = *(const float4*)&Eq[r * HD + d4];
    }
    for (int i = t; i < NREL; i += 256) eeS[i] = ee[i];
    {
        int l = t >> 4, d4 = (t & 15) * 4;
        *(float4*)&Qs[l][d4] = *(const float4*)&Q[(g0 + l) * HD + d4];
        *(float4*)&Ks[l][d4] = *(const float4*)&K[(g0 + l) * HD + d4];
    }
    __syncthreads();
    const int l = t >> 4, rr = t & 15;
#pragma unroll
    for (int j = 0; j < 9; j++) {
        int r = rr + 16 * j;
        if (r < NREL) {
            float aq = 0.f, ak = 0.f;
#pragma unroll
            for (int d = 0; d < HD; d += 4) {
                float4 q4 = *(const float4*)&Qs[l][d];
                float4 k4 = *(const float4*)&Ks[l][d];
                float4 e4 = *(const float4*)&EkS[r][d];
                float4 f4 = *(const float4*)&EqS[r][d];
                aq += q4.x * e4.x + q4.y * e4.y + q4.z * e4.z + q4.w * e4.w;
                ak += k4.x * f4.x + k4.y * f4.y + k4.z * f4.z + k4.w * f4.w;
            }
            qEe[(size_t)(g0 + l) * ER + r] = f2bf(aq + eeS[r]);
            kEb[(size_t)(g0 + l) * ER + r] = f2bf(ak);
        }
    }
}

// ---------------- attention (MFMA): block = (b,h,64 l-rows), 4 waves x 16 rows
__global__ __launch_bounds__(256) void attn_k(const float* __restrict__ Q,
                                              const float* __restrict__ K,
                                              const float* __restrict__ V,
                                              const unsigned short* __restrict__ qEg,
                                              const unsigned short* __restrict__ kEg,
                                              unsigned short* __restrict__ aRg,
                                              float* __restrict__ out) {
    __shared__ __align__(16) char un[18432];     // Qstage | (Kt,Vtt,kEt)
    __shared__ short qEeS[64][ER];               // 17408
    __shared__ short Pt[4][16][40];              // 5120
    __shared__ short aRs[4][16][ER];             // 17408
    __shared__ float invs[4][16];                // 256

    float (*Qstage)[64] = (float(*)[64])un;                 // 16384
    short (*Kt)[72]  = (short(*)[72])un;                    // 4608
    short (*Vtt)[40] = (short(*)[40])(un + 4608);           // 5120
    short (*kEt)[ER] = (short(*)[ER])(un + 9728);           // 8704

    const int t = threadIdx.x;
    const int lt = blockIdx.x & 7;
    const int bh = blockIdx.x >> 3;
    const int b = bh >> 4, h = bh & 15;
    const int bS = b * SEQ;
    const int l0 = lt * 64;
    const int w = t >> 6;
    const int lane = t & 63;
    const int ln = lane & 15;
    const int kg = lane >> 4;
    const int l0w = l0 + w * 16;

    // ---- startup staging
    for (int i = t; i < 1024; i += 256) {
        int r = i >> 4, c = (i & 15) << 2;
        *(float4*)&Qstage[r][c] = *(const float4*)&Q[(size_t)(bS + l0 + r) * 1024 + h * 64 + c];
    }
    for (int i = t; i < 1088; i += 256) {
        int r = i / 17, c = i % 17;
        ((uint4*)&qEeS[r][0])[c] = ((const uint4*)&qEg[(size_t)((bS + l0 + r) * NH + h) * ER])[c];
    }
    for (int i = t; i < 4352; i += 256) ((unsigned*)aRs)[i] = 0u;
    __syncthreads();

    // Q fragments (read before loop's first barrier; Kt overwrites Qstage after it)
    bf16x8 qf0, qf1;
#pragma unroll
    for (int j = 0; j < 8; j++) {
        qf0[j] = (short)f2bf(Qstage[w * 16 + ln][kg * 8 + j]);
        qf1[j] = (short)f2bf(Qstage[w * 16 + ln][32 + kg * 8 + j]);
    }

    f32x4 of[4];
#pragma unroll
    for (int nt = 0; nt < 4; nt++) of[nt] = (f32x4){0.f, 0.f, 0.f, 0.f};
    float rs[4]   = {0.f, 0.f, 0.f, 0.f};
    float s0[4]   = {0.f, 0.f, 0.f, 0.f};
    float s128[4] = {0.f, 0.f, 0.f, 0.f};

    for (int mt = 0; mt < 16; mt++) {
        const int m0 = mt * 32;
        __syncthreads();
        // stage K (row-major bf16) and V (transposed bf16)
        for (int i = t; i < 512; i += 256) {
            int r = i >> 4, c = (i & 15) << 2;
            float4 kv = *(const float4*)&K[(size_t)(bS + m0 + r) * 1024 + h * 64 + c];
            short4 k4 = {(short)f2bf(kv.x), (short)f2bf(kv.y), (short)f2bf(kv.z), (short)f2bf(kv.w)};
            *(short4*)&Kt[r][c] = k4;
            float4 vv = *(const float4*)&V[(size_t)(bS + m0 + r) * 1024 + h * 64 + c];
            Vtt[c + 0][r] = (short)f2bf(vv.x);
            Vtt[c + 1][r] = (short)f2bf(vv.y);
            Vtt[c + 2][r] = (short)f2bf(vv.z);
            Vtt[c + 3][r] = (short)f2bf(vv.w);
        }
        for (int i = t; i < 544; i += 256) {
            int r = i / 17, c = i % 17;
            ((uint4*)&kEt[r][0])[c] = ((const uint4*)&kEg[(size_t)((bS + m0 + r) * NH + h) * ER])[c];
        }
        __syncthreads();

        // QK^T + bias + exp; write P (bf16) + aR band
#pragma unroll
        for (int sub = 0; sub < 2; sub++) {
            f32x4 acc = (f32x4){0.f, 0.f, 0.f, 0.f};
            acc = __builtin_amdgcn_mfma_f32_16x16x32_bf16(qf0, *(bf16x8*)&Kt[sub * 16 + ln][kg * 8], acc, 0, 0, 0);
            acc = __builtin_amdgcn_mfma_f32_16x16x32_bf16(qf1, *(bf16x8*)&Kt[sub * 16 + ln][32 + kg * 8], acc, 0, 0, 0);
            const int mloc = sub * 16 + ln;
            const int m = m0 + mloc;
#pragma unroll
            for (int reg = 0; reg < 4; reg++) {
                const int lr = kg * 4 + reg;                     // wave-local row (C/D layout, verified)
                const int dlt = (l0w + lr) - m;
                const int r = dlt < -64 ? 0 : (dlt > 64 ? 128 : dlt + 64);
                float lg = (acc[reg] + bf2f((unsigned short)qEeS[w * 16 + lr][r])
                                     + bf2f((unsigned short)kEt[mloc][r])) * SCALE;
                float p = __expf(lg);
                rs[reg] += p;
                if (dlt >= 64)       s128[reg] += p;
                else if (dlt <= -64) s0[reg]   += p;
                else                 aRs[w][lr][r] = (short)f2bf(p);   // unique (lr,r): race-free
                Pt[w][lr][mloc] = (short)f2bf(p);
            }
        }
        asm volatile("" ::: "memory");   // order in-wave Pt stores vs vector reads
        // PV
        bf16x8 pf = *(bf16x8*)&Pt[w][ln][kg * 8];
#pragma unroll
        for (int nt = 0; nt < 4; nt++) {
            of[nt] = __builtin_amdgcn_mfma_f32_16x16x32_bf16(pf, *(bf16x8*)&Vtt[nt * 16 + ln][kg * 8], of[nt], 0, 0, 0);
        }
    }

    __syncthreads();
    // row reductions across the 16 lanes sharing rows
#pragma unroll
    for (int reg = 0; reg < 4; reg++) {
        for (int off = 1; off <= 8; off <<= 1) {
            rs[reg]   += __shfl_xor(rs[reg], off);
            s0[reg]   += __shfl_xor(s0[reg], off);
            s128[reg] += __shfl_xor(s128[reg], off);
        }
    }
    float inv[4];
#pragma unroll
    for (int reg = 0; reg < 4; reg++) inv[reg] = 1.0f / rs[reg];

    if (ln == 0) {
#pragma unroll
        for (int reg = 0; reg < 4; reg++) {
            aRs[w][kg * 4 + reg][0]   = (short)f2bf(s0[reg]   * inv[reg]);  // normalized edges
            aRs[w][kg * 4 + reg][128] = (short)f2bf(s128[reg] * inv[reg]);
            invs[w][kg * 4 + reg] = inv[reg];
        }
    }
    __syncthreads();
    // normalize band cols 1..127
    {
        const int row = lane >> 2;
        const float sc = invs[w][row];
#pragma unroll
        for (int kk = 0; kk < 32; kk++) {
            int c = (lane & 3) * 32 + kk;
            if (c >= 1) aRs[w][row][c] = (short)f2bf(bf2f((unsigned short)aRs[w][row][c]) * sc);
        }
    }
    // normalize PV accumulators
#pragma unroll
    for (int nt = 0; nt < 4; nt++)
#pragma unroll
        for (int reg = 0; reg < 4; reg++) of[nt][reg] *= inv[reg];
    __syncthreads();

    // store PV part of out
#pragma unroll
    for (int nt = 0; nt < 4; nt++)
#pragma unroll
        for (int reg = 0; reg < 4; reg++)
            out[(size_t)(bS + l0w + kg * 4 + reg) * 1024 + h * 64 + nt * 16 + ln] = of[nt][reg];

    // dump normalized aR rows for rel_av
    for (int i = lane; i < 272; i += 64) {
        int r = i / 17, c = i % 17;
        ((uint4*)&aRg[(size_t)((bS + l0w + r) * NH + h) * ER])[c] = ((const uint4*)&aRs[w][r][0])[c];
    }
}

// ---------------- out += aRn @ Ev  (rows g2 = (b*S+s)*H+h; out viewed as [131072][64])
__global__ __launch_bounds__(256) void rel_av(const unsigned short* __restrict__ aRg,
                                              const float* __restrict__ Ev,
                                              float* __restrict__ out) {
    __shared__ short EvT[64][ER];     // [d][r]
    __shared__ short aRst[64][ER];
    const int t = threadIdx.x;
    const int g0 = blockIdx.x * 64;
    const int w = t >> 6, lane = t & 63, ln = lane & 15, kg = lane >> 4;

    for (int i = t; i < 2048; i += 256) {
        int r = i >> 4, c = (i & 15) << 2;
        float4 e = *(const float4*)&Ev[r * HD + c];
        EvT[c + 0][r] = (short)f2bf(e.x);
        EvT[c + 1][r] = (short)f2bf(e.y);
        EvT[c + 2][r] = (short)f2bf(e.z);
        EvT[c + 3][r] = (short)f2bf(e.w);
    }
    for (int i = t; i < 1088; i += 256) {
        int r = i / 17, c = i % 17;
        ((uint4*)&aRst[r][0])[c] = ((const uint4*)&aRg[(size_t)(g0 + r) * ER])[c];
    }
    __syncthreads();

    f32x4 of[4];
#pragma unroll
    for (int nt = 0; nt < 4; nt++) of[nt] = (f32x4){0.f, 0.f, 0.f, 0.f};
#pragma unroll
    for (int nt = 0; nt < 4; nt++)
#pragma unroll
        for (int ks = 0; ks < 4; ks++)
            of[nt] = __builtin_amdgcn_mfma_f32_16x16x32_bf16(*(bf16x8*)&aRst[w * 16 + ln][ks * 32 + kg * 8],
                                                             *(bf16x8*)&EvT[nt * 16 + ln][ks * 32 + kg * 8],
                                                             of[nt], 0, 0, 0);
#pragma unroll
    for (int nt = 0; nt < 4; nt++) {
        float ev128 = Ev[128 * HD + nt * 16 + ln];
#pragma unroll
        for (int reg = 0; reg < 4; reg++) {
            int lr = w * 16 + kg * 4 + reg;
            float a128 = bf2f((unsigned short)aRst[lr][128]);
            out[(size_t)(g0 + lr) * HD + nt * 16 + ln] += of[nt][reg] + a128 * ev128;
        }
    }
}

extern "C" void kernel_launch(void* const* d_in, const int* in_sizes, int n_in,
                              void* d_out, int out_size, void* d_ws, size_t ws_size,
                              hipStream_t stream) {
    const float* x  = (const float*)d_in[0];
    const float* Wq = (const float*)d_in[1];
    const float* Wk = (const float*)d_in[2];
    const float* Wv = (const float*)d_in[3];
    const float* Eq = (const float*)d_in[4];
    const float* Ek = (const float*)d_in[5];
    const float* Ev = (const float*)d_in[6];
    float* out = (float*)d_out;
    char* ws = (char*)d_ws;

    float* Qm = (float*)(ws);                                 // 33,554,432
    float* Km = (float*)(ws + 33554432ull);                   // 33,554,432
    float* Vm = (float*)(ws + 67108864ull);                   // 33,554,432
    unsigned short* qEe = (unsigned short*)(ws + 100663296ull);   // 35,651,584
    unsigned short* kEb = (unsigned short*)(ws + 136314880ull);   // 35,651,584
    float* ee = (float*)(ws + 171966464ull);                  // 528
    unsigned short* aRg = (unsigned short*)(ws + 171967232ull);   // 35,651,584  (~207.6 MB total)

    proj_gemm<<<1024, 256, 0, stream>>>(x, Wq, Qm);
    proj_gemm<<<1024, 256, 0, stream>>>(x, Wk, Km);
    proj_gemm<<<1024, 256, 0, stream>>>(x, Wv, Vm);
    ee_k<<<1, 256, 0, stream>>>(Eq, Ek, ee);
    qk_e<<<8192, 256, 0, stream>>>(Qm, Km, Eq, Ek, ee, qEe, kEb);
    attn_k<<<2048, 256, 0, stream>>>(Qm, Km, Vm, qEe, kEb, aRg, out);
    rel_av<<<2048, 256, 0, stream>>>(aRg, Ev, out);
}

// Round 3
// 515.701 us; speedup vs baseline: 4.5637x; 2.6168x over previous
//
#include <hip/hip_runtime.h>

#define SEQ 512
#define NH 16
#define HD 64
#define NREL 129
#define ER 136          // padded bf16 row stride (136*2 = 272 B, 16B-aligned)
#define SCALE 0.125f

typedef __attribute__((ext_vector_type(8))) short bf16x8;
typedef __attribute__((ext_vector_type(4))) float f32x4;

__device__ __forceinline__ unsigned short f2bf(float x) {
    unsigned u = __builtin_bit_cast(unsigned, x);
    u += 0x7FFFu + ((u >> 16) & 1u);
    return (unsigned short)(u >> 16);
}
__device__ __forceinline__ float bf2f(unsigned short s) {
    unsigned u = ((unsigned)s) << 16;
    return __builtin_bit_cast(float, u);
}
__device__ __forceinline__ unsigned pack2(float a, float b) {
    return (unsigned)f2bf(a) | ((unsigned)f2bf(b) << 16);
}

// ---------------- x (8192x1024 f32) -> bf16
__global__ __launch_bounds__(256) void conv_x(const float* __restrict__ in,
                                              unsigned short* __restrict__ ob) {
    size_t i = (size_t)blockIdx.x * 256 + threadIdx.x;   // one 8-elem chunk
    const float4* p = (const float4*)in + i * 2;
    float4 a = p[0], b = p[1];
    uint4 o;
    o.x = pack2(a.x, a.y); o.y = pack2(a.z, a.w);
    o.z = pack2(b.x, b.y); o.w = pack2(b.z, b.w);
    ((uint4*)ob)[i] = o;
}

// ---------------- W(q,k,v) (1024x1024 f32 each) -> WbT [3072][1024] bf16 (transposed)
__global__ __launch_bounds__(256) void conv_w(const float* __restrict__ Wq,
                                              const float* __restrict__ Wk,
                                              const float* __restrict__ Wv,
                                              unsigned short* __restrict__ WbT) {
    __shared__ float Ws[64][65];
    const int t = threadIdx.x;
    const int mi = blockIdx.x >> 8;
    const int rem = blockIdx.x & 255;
    const int k0 = (rem >> 4) * 64, n0 = (rem & 15) * 64;
    const float* W = mi == 0 ? Wq : (mi == 1 ? Wk : Wv);
    const int rr = t >> 4, c4 = (t & 15) * 4;
#pragma unroll
    for (int j = 0; j < 4; j++) {
        float4 v = *(const float4*)&W[(size_t)(k0 + rr + j * 16) * 1024 + n0 + c4];
        Ws[rr + j * 16][c4 + 0] = v.x; Ws[rr + j * 16][c4 + 1] = v.y;
        Ws[rr + j * 16][c4 + 2] = v.z; Ws[rr + j * 16][c4 + 3] = v.w;
    }
    __syncthreads();
    const int n = t >> 2;
    for (int cc = (t & 3); cc < 8; cc += 4) {
        unsigned short tmp[8];
#pragma unroll
        for (int j = 0; j < 8; j++) tmp[j] = f2bf(Ws[cc * 8 + j][n]);
        *(uint4*)&WbT[(size_t)(mi * 1024 + n0 + n) * 1024 + k0 + cc * 8] = *(uint4*)tmp;
    }
}

// ---------------- Eq/Ek (129x64 f32) -> bf16 [144][64], zero-padded rows
__global__ void conv_e(const float* __restrict__ Eq, const float* __restrict__ Ek,
                       unsigned short* __restrict__ Eqb, unsigned short* __restrict__ Ekb) {
    const int t = threadIdx.x;
    for (int i = t; i < 1152; i += 256) {
        int r = i >> 3, c8 = (i & 7) * 8;
        uint4 oq = {0, 0, 0, 0}, ok = {0, 0, 0, 0};
        if (r < NREL) {
            float4 a = *(const float4*)&Eq[r * 64 + c8];
            float4 b = *(const float4*)&Eq[r * 64 + c8 + 4];
            oq.x = pack2(a.x, a.y); oq.y = pack2(a.z, a.w);
            oq.z = pack2(b.x, b.y); oq.w = pack2(b.z, b.w);
            float4 c = *(const float4*)&Ek[r * 64 + c8];
            float4 d = *(const float4*)&Ek[r * 64 + c8 + 4];
            ok.x = pack2(c.x, c.y); ok.y = pack2(c.z, c.w);
            ok.z = pack2(d.x, d.y); ok.w = pack2(d.z, d.w);
        }
        ((uint4*)Eqb)[i] = oq;
        ((uint4*)Ekb)[i] = ok;
    }
}

// ---------------- ee[r] = dot(Eq[r], Ek[r])  (f32)
__global__ void ee_k(const float* __restrict__ Eq, const float* __restrict__ Ek,
                     float* __restrict__ ee) {
    int r = threadIdx.x;
    if (r < NREL) {
        float s = 0.f;
        for (int d = 0; d < HD; d++) s += Eq[r * HD + d] * Ek[r * HD + d];
        ee[r] = s;
    }
}

// ---------------- fused projection: [8192x3072] = xb[8192x1024] @ W; 128x128 tile, BK=64
__global__ __launch_bounds__(256) void proj_mfma(const unsigned short* __restrict__ xb,
                                                 const unsigned short* __restrict__ WbT,
                                                 unsigned short* __restrict__ Qb,
                                                 unsigned short* __restrict__ Kb,
                                                 unsigned short* __restrict__ Vb) {
    __shared__ __align__(16) char smem[34816];
    uint4* lds = (uint4*)smem;               // As [0,1024), Bs [1024,2048)
    short (*cs)[136] = (short(*)[136])smem;  // epilogue C tile

    const int t = threadIdx.x;
    const int bm = blockIdx.x & 63;
    const int bn = blockIdx.x >> 6;          // 0..23
    const int m0 = bm * 128;
    const int n0g = bn * 128;
    const int w = t >> 6, lane = t & 63, ln = lane & 15, kg = lane >> 4;
    const int wm = w >> 1, wn = w & 1;

    const int sr = t >> 1;                   // staging row 0..127
    const int sc = (t & 1) * 4;              // base chunk
    const uint4* xg = (const uint4*)xb + (size_t)(m0 + sr) * 128 + sc;
    const uint4* wg = (const uint4*)WbT + (size_t)(n0g + sr) * 128 + sc;
    uint4* asw = &lds[sr * 8];
    uint4* bsw = &lds[1024 + sr * 8];
    const int sx = sr & 7;

    f32x4 acc[4][4];
#pragma unroll
    for (int i = 0; i < 4; i++)
#pragma unroll
        for (int j = 0; j < 4; j++) acc[i][j] = (f32x4){0.f, 0.f, 0.f, 0.f};

    for (int k0 = 0; k0 < 128; k0 += 8) {    // k in 16B chunks
        uint4 av[4], bv[4];
#pragma unroll
        for (int j = 0; j < 4; j++) { av[j] = xg[k0 + j]; bv[j] = wg[k0 + j]; }
        __syncthreads();
#pragma unroll
        for (int j = 0; j < 4; j++) {
            asw[(sc + j) ^ sx] = av[j];
            bsw[(sc + j) ^ sx] = bv[j];
        }
        __syncthreads();
#pragma unroll
        for (int ks = 0; ks < 2; ks++) {
            bf16x8 af[4], bf[4];
            const int ch = (ks * 4 + kg) ^ (ln & 7);
#pragma unroll
            for (int i = 0; i < 4; i++) af[i] = *(bf16x8*)&lds[(wm * 64 + i * 16 + ln) * 8 + ch];
#pragma unroll
            for (int j = 0; j < 4; j++) bf[j] = *(bf16x8*)&lds[1024 + (wn * 64 + j * 16 + ln) * 8 + ch];
#pragma unroll
            for (int i = 0; i < 4; i++)
#pragma unroll
                for (int j = 0; j < 4; j++)
                    acc[i][j] = __builtin_amdgcn_mfma_f32_16x16x32_bf16(af[i], bf[j], acc[i][j], 0, 0, 0);
        }
    }
    __syncthreads();
    // epilogue: C tile to LDS, then coalesced store
#pragma unroll
    for (int i = 0; i < 4; i++)
#pragma unroll
        for (int j = 0; j < 4; j++)
#pragma unroll
            for (int reg = 0; reg < 4; reg++)
                cs[wm * 64 + i * 16 + kg * 4 + reg][wn * 64 + j * 16 + ln] = (short)f2bf(acc[i][j][reg]);
    __syncthreads();
    const int which = n0g >> 10;
    unsigned short* outp = which == 0 ? Qb : (which == 1 ? Kb : Vb);
    const int ncol0 = n0g & 1023;
    const int r = t >> 1, half = t & 1;
    uint4* orow = (uint4*)(outp + (size_t)(m0 + r) * 1024 + ncol0 + half * 64);
    const uint4* crow = (const uint4*)&cs[r][half * 64];
#pragma unroll
    for (int j = 0; j < 8; j++) orow[j] = crow[j];
}

// ---------------- qEe/kEb via MFMA: block = 64 g-rows, wave = 16 rows x 144 r-cols
__global__ __launch_bounds__(256) void qk_e_mfma(const unsigned short* __restrict__ Qb,
                                                 const unsigned short* __restrict__ Kb,
                                                 const unsigned short* __restrict__ Ekb,
                                                 const unsigned short* __restrict__ Eqb,
                                                 const float* __restrict__ ee,
                                                 unsigned short* __restrict__ qEe,
                                                 unsigned short* __restrict__ kEb) {
    __shared__ uint4 lds[3328];   // Qt 512 | Kt 512 | EkS 1152 | EqS 1152
    __shared__ float eeS[136];
    uint4* Qt = lds;
    uint4* Kt = lds + 512;
    uint4* EkS = lds + 1024;
    uint4* EqS = lds + 2176;
    const int t = threadIdx.x, w = t >> 6, lane = t & 63, ln = lane & 15, kg = lane >> 4;
    const int g0 = blockIdx.x * 64;

    {
        int r = t >> 2, cb = (t & 3) * 2;
        const uint4* qg = (const uint4*)Qb + (size_t)(g0 + r) * 8;
        const uint4* kgp = (const uint4*)Kb + (size_t)(g0 + r) * 8;
#pragma unroll
        for (int j = 0; j < 2; j++) {
            int c = cb + j;
            Qt[r * 8 + (c ^ (r & 7))] = qg[c];
            Kt[r * 8 + (c ^ (r & 7))] = kgp[c];
        }
    }
    for (int i = t; i < 1152; i += 256) {
        int r = i >> 3, c = i & 7;
        EkS[r * 8 + (c ^ (r & 7))] = ((const uint4*)Ekb)[i];
        EqS[r * 8 + (c ^ (r & 7))] = ((const uint4*)Eqb)[i];
    }
    if (t < NREL) eeS[t] = ee[t];
    __syncthreads();

    const int lx = ln & 7;
    // ---- phase 1: qE = Q @ Ek^T (+ee)
    {
        bf16x8 a0 = *(bf16x8*)&Qt[(w * 16 + ln) * 8 + (kg ^ lx)];
        bf16x8 a1 = *(bf16x8*)&Qt[(w * 16 + ln) * 8 + ((4 + kg) ^ lx)];
        f32x4 acc[9];
#pragma unroll
        for (int j = 0; j < 9; j++) acc[j] = (f32x4){0.f, 0.f, 0.f, 0.f};
#pragma unroll
        for (int j = 0; j < 9; j++) {
            acc[j] = __builtin_amdgcn_mfma_f32_16x16x32_bf16(a0, *(bf16x8*)&EkS[(j * 16 + ln) * 8 + (kg ^ lx)], acc[j], 0, 0, 0);
            acc[j] = __builtin_amdgcn_mfma_f32_16x16x32_bf16(a1, *(bf16x8*)&EkS[(j * 16 + ln) * 8 + ((4 + kg) ^ lx)], acc[j], 0, 0, 0);
        }
#pragma unroll
        for (int j = 0; j < 9; j++) {
            int r = j * 16 + ln;
            if (r <= 128) {
#pragma unroll
                for (int reg = 0; reg < 4; reg++) {
                    int g = g0 + w * 16 + kg * 4 + reg;
                    qEe[(size_t)g * ER + r] = f2bf(acc[j][reg] + eeS[r]);
                }
            }
        }
    }
    // ---- phase 2: kE = K @ Eq^T
    {
        bf16x8 a0 = *(bf16x8*)&Kt[(w * 16 + ln) * 8 + (kg ^ lx)];
        bf16x8 a1 = *(bf16x8*)&Kt[(w * 16 + ln) * 8 + ((4 + kg) ^ lx)];
        f32x4 acc[9];
#pragma unroll
        for (int j = 0; j < 9; j++) acc[j] = (f32x4){0.f, 0.f, 0.f, 0.f};
#pragma unroll
        for (int j = 0; j < 9; j++) {
            acc[j] = __builtin_amdgcn_mfma_f32_16x16x32_bf16(a0, *(bf16x8*)&EqS[(j * 16 + ln) * 8 + (kg ^ lx)], acc[j], 0, 0, 0);
            acc[j] = __builtin_amdgcn_mfma_f32_16x16x32_bf16(a1, *(bf16x8*)&EqS[(j * 16 + ln) * 8 + ((4 + kg) ^ lx)], acc[j], 0, 0, 0);
        }
#pragma unroll
        for (int j = 0; j < 9; j++) {
            int r = j * 16 + ln;
            if (r <= 128) {
#pragma unroll
                for (int reg = 0; reg < 4; reg++) {
                    int g = g0 + w * 16 + kg * 4 + reg;
                    kEb[(size_t)g * ER + r] = f2bf(acc[j][reg]);
                }
            }
        }
    }
}

// ---------------- attention (MFMA): block = (b,h,64 l-rows), 4 waves x 16 rows
__global__ __launch_bounds__(256) void attn_k(const unsigned short* __restrict__ Q,
                                              const unsigned short* __restrict__ K,
                                              const unsigned short* __restrict__ V,
                                              const unsigned short* __restrict__ qEg,
                                              const unsigned short* __restrict__ kEg,
                                              unsigned short* __restrict__ aRg,
                                              float* __restrict__ out) {
    __shared__ __align__(16) char un[18432];
    __shared__ short qEeS[64][ER];
    __shared__ short Pt[4][16][40];
    __shared__ short aRs[4][16][ER];
    __shared__ float invs[4][16];

    short (*Qsb)[64] = (short(*)[64])un;            // 8192
    short (*Kt)[72]  = (short(*)[72])un;            // 4608
    short (*Vtt)[40] = (short(*)[40])(un + 4608);   // 5120
    short (*kEt)[ER] = (short(*)[ER])(un + 9728);   // 8704

    const int t = threadIdx.x;
    const int lt = blockIdx.x & 7;
    const int bh = blockIdx.x >> 3;
    const int b = bh >> 4, h = bh & 15;
    const int bS = b * SEQ;
    const int l0 = lt * 64;
    const int w = t >> 6;
    const int lane = t & 63;
    const int ln = lane & 15;
    const int kg = lane >> 4;
    const int l0w = l0 + w * 16;

    for (int i = t; i < 512; i += 256) {
        int r = i >> 3, c8 = (i & 7) * 8;
        *(uint4*)&Qsb[r][c8] = *(const uint4*)&Q[(size_t)(bS + l0 + r) * 1024 + h * 64 + c8];
    }
    for (int i = t; i < 1088; i += 256) {
        int r = i / 17, c = i % 17;
        ((uint4*)&qEeS[r][0])[c] = ((const uint4*)&qEg[(size_t)((bS + l0 + r) * NH + h) * ER])[c];
    }
    for (int i = t; i < 4352; i += 256) ((unsigned*)aRs)[i] = 0u;
    __syncthreads();

    bf16x8 qf0 = *(bf16x8*)&Qsb[w * 16 + ln][kg * 8];
    bf16x8 qf1 = *(bf16x8*)&Qsb[w * 16 + ln][32 + kg * 8];

    f32x4 of[4];
#pragma unroll
    for (int nt = 0; nt < 4; nt++) of[nt] = (f32x4){0.f, 0.f, 0.f, 0.f};
    float rs[4]   = {0.f, 0.f, 0.f, 0.f};
    float s0[4]   = {0.f, 0.f, 0.f, 0.f};
    float s128[4] = {0.f, 0.f, 0.f, 0.f};

    for (int mt = 0; mt < 16; mt++) {
        const int m0 = mt * 32;
        __syncthreads();
        {
            int r = t >> 3, c8 = (t & 7) * 8;
            *(uint4*)&Kt[r][c8] = *(const uint4*)&K[(size_t)(bS + m0 + r) * 1024 + h * 64 + c8];
            uint4 vv = *(const uint4*)&V[(size_t)(bS + m0 + r) * 1024 + h * 64 + c8];
            short* vs = (short*)&vv;
#pragma unroll
            for (int j = 0; j < 8; j++) Vtt[c8 + j][r] = vs[j];
        }
        for (int i = t; i < 544; i += 256) {
            int r = i / 17, c = i % 17;
            ((uint4*)&kEt[r][0])[c] = ((const uint4*)&kEg[(size_t)((bS + m0 + r) * NH + h) * ER])[c];
        }
        __syncthreads();

#pragma unroll
        for (int sub = 0; sub < 2; sub++) {
            f32x4 acc = (f32x4){0.f, 0.f, 0.f, 0.f};
            acc = __builtin_amdgcn_mfma_f32_16x16x32_bf16(qf0, *(bf16x8*)&Kt[sub * 16 + ln][kg * 8], acc, 0, 0, 0);
            acc = __builtin_amdgcn_mfma_f32_16x16x32_bf16(qf1, *(bf16x8*)&Kt[sub * 16 + ln][32 + kg * 8], acc, 0, 0, 0);
            const int mloc = sub * 16 + ln;
            const int m = m0 + mloc;
#pragma unroll
            for (int reg = 0; reg < 4; reg++) {
                const int lr = kg * 4 + reg;
                const int dlt = (l0w + lr) - m;
                const int r = dlt < -64 ? 0 : (dlt > 64 ? 128 : dlt + 64);
                float lg = (acc[reg] + bf2f((unsigned short)qEeS[w * 16 + lr][r])
                                     + bf2f((unsigned short)kEt[mloc][r])) * SCALE;
                float p = __expf(lg);
                rs[reg] += p;
                if (dlt >= 64)       s128[reg] += p;
                else if (dlt <= -64) s0[reg]   += p;
                else                 aRs[w][lr][r] = (short)f2bf(p);
                Pt[w][lr][mloc] = (short)f2bf(p);
            }
        }
        asm volatile("" ::: "memory");
        bf16x8 pf = *(bf16x8*)&Pt[w][ln][kg * 8];
#pragma unroll
        for (int nt = 0; nt < 4; nt++) {
            of[nt] = __builtin_amdgcn_mfma_f32_16x16x32_bf16(pf, *(bf16x8*)&Vtt[nt * 16 + ln][kg * 8], of[nt], 0, 0, 0);
        }
    }

    __syncthreads();
#pragma unroll
    for (int reg = 0; reg < 4; reg++) {
        for (int off = 1; off <= 8; off <<= 1) {
            rs[reg]   += __shfl_xor(rs[reg], off);
            s0[reg]   += __shfl_xor(s0[reg], off);
            s128[reg] += __shfl_xor(s128[reg], off);
        }
    }
    float inv[4];
#pragma unroll
    for (int reg = 0; reg < 4; reg++) inv[reg] = 1.0f / rs[reg];

    if (ln == 0) {
#pragma unroll
        for (int reg = 0; reg < 4; reg++) {
            aRs[w][kg * 4 + reg][0]   = (short)f2bf(s0[reg]   * inv[reg]);
            aRs[w][kg * 4 + reg][128] = (short)f2bf(s128[reg] * inv[reg]);
            invs[w][kg * 4 + reg] = inv[reg];
        }
    }
    __syncthreads();
    {
        const int row = lane >> 2;
        const float sc = invs[w][row];
#pragma unroll
        for (int kk = 0; kk < 32; kk++) {
            int c = (lane & 3) * 32 + kk;
            if (c >= 1) aRs[w][row][c] = (short)f2bf(bf2f((unsigned short)aRs[w][row][c]) * sc);
        }
    }
#pragma unroll
    for (int nt = 0; nt < 4; nt++)
#pragma unroll
        for (int reg = 0; reg < 4; reg++) of[nt][reg] *= inv[reg];
    __syncthreads();

#pragma unroll
    for (int nt = 0; nt < 4; nt++)
#pragma unroll
        for (int reg = 0; reg < 4; reg++)
            out[(size_t)(bS + l0w + kg * 4 + reg) * 1024 + h * 64 + nt * 16 + ln] = of[nt][reg];

    for (int i = lane; i < 272; i += 64) {
        int r = i / 17, c = i % 17;
        ((uint4*)&aRg[(size_t)((bS + l0w + r) * NH + h) * ER])[c] = ((const uint4*)&aRs[w][r][0])[c];
    }
}

// ---------------- out += aRn @ Ev
__global__ __launch_bounds__(256) void rel_av(const unsigned short* __restrict__ aRg,
                                              const float* __restrict__ Ev,
                                              float* __restrict__ out) {
    __shared__ short EvT[64][ER];
    __shared__ short aRst[64][ER];
    const int t = threadIdx.x;
    const int g0 = blockIdx.x * 64;
    const int w = t >> 6, lane = t & 63, ln = lane & 15, kg = lane >> 4;

    for (int i = t; i < 2048; i += 256) {
        int r = i >> 4, c = (i & 15) << 2;
        float4 e = *(const float4*)&Ev[r * HD + c];
        EvT[c + 0][r] = (short)f2bf(e.x);
        EvT[c + 1][r] = (short)f2bf(e.y);
        EvT[c + 2][r] = (short)f2bf(e.z);
        EvT[c + 3][r] = (short)f2bf(e.w);
    }
    for (int i = t; i < 1088; i += 256) {
        int r = i / 17, c = i % 17;
        ((uint4*)&aRst[r][0])[c] = ((const uint4*)&aRg[(size_t)(g0 + r) * ER])[c];
    }
    __syncthreads();

    f32x4 of[4];
#pragma unroll
    for (int nt = 0; nt < 4; nt++) of[nt] = (f32x4){0.f, 0.f, 0.f, 0.f};
#pragma unroll
    for (int nt = 0; nt < 4; nt++)
#pragma unroll
        for (int ks = 0; ks < 4; ks++)
            of[nt] = __builtin_amdgcn_mfma_f32_16x16x32_bf16(*(bf16x8*)&aRst[w * 16 + ln][ks * 32 + kg * 8],
                                                             *(bf16x8*)&EvT[nt * 16 + ln][ks * 32 + kg * 8],
                                                             of[nt], 0, 0, 0);
#pragma unroll
    for (int nt = 0; nt < 4; nt++) {
        float ev128 = Ev[128 * HD + nt * 16 + ln];
#pragma unroll
        for (int reg = 0; reg < 4; reg++) {
            int lr = w * 16 + kg * 4 + reg;
            float a128 = bf2f((unsigned short)aRst[lr][128]);
            out[(size_t)(g0 + lr) * HD + nt * 16 + ln] += of[nt][reg] + a128 * ev128;
        }
    }
}

extern "C" void kernel_launch(void* const* d_in, const int* in_sizes, int n_in,
                              void* d_out, int out_size, void* d_ws, size_t ws_size,
                              hipStream_t stream) {
    const float* x  = (const float*)d_in[0];
    const float* Wq = (const float*)d_in[1];
    const float* Wk = (const float*)d_in[2];
    const float* Wv = (const float*)d_in[3];
    const float* Eq = (const float*)d_in[4];
    const float* Ek = (const float*)d_in[5];
    const float* Ev = (const float*)d_in[6];
    float* out = (float*)d_out;
    char* ws = (char*)d_ws;

    unsigned short* Qb  = (unsigned short*)(ws);                    // 16,777,216
    unsigned short* Kb  = (unsigned short*)(ws + 16777216ull);
    unsigned short* Vb  = (unsigned short*)(ws + 33554432ull);
    unsigned short* xb  = (unsigned short*)(ws + 50331648ull);      // 16,777,216
    unsigned short* WbT = (unsigned short*)(ws + 67108864ull);      // 6,291,456
    unsigned short* Ekb = (unsigned short*)(ws + 73400320ull);      // 18,432
    unsigned short* Eqb = (unsigned short*)(ws + 73418752ull);      // 18,432
    float*          ee  = (float*)(ws + 73437184ull);               // 576
    unsigned short* qEe = (unsigned short*)(ws + 73437760ull);      // 35,651,584
    unsigned short* kEb = (unsigned short*)(ws + 109089344ull);     // 35,651,584
    unsigned short* aRg = (unsigned short*)(ws + 144740928ull);     // 35,651,584 (end ~180.4 MB)

    conv_x<<<4096, 256, 0, stream>>>(x, xb);
    conv_w<<<768, 256, 0, stream>>>(Wq, Wk, Wv, WbT);
    conv_e<<<1, 256, 0, stream>>>(Eq, Ek, Eqb, Ekb);
    ee_k<<<1, 256, 0, stream>>>(Eq, Ek, ee);
    proj_mfma<<<1536, 256, 0, stream>>>(xb, WbT, Qb, Kb, Vb);
    qk_e_mfma<<<2048, 256, 0, stream>>>(Qb, Kb, Ekb, Eqb, ee, qEe, kEb);
    attn_k<<<2048, 256, 0, stream>>>(Qb, Kb, Vb, qEe, kEb, aRg, out);
    rel_av<<<2048, 256, 0, stream>>>(aRg, Ev, out);
}

// Round 4
// 357.261 us; speedup vs baseline: 6.5876x; 1.4435x over previous
//
#include <hip/hip_runtime.h>

#define SEQ 512
#define NH 16
#define HD 64
#define NREL 129
#define ER 136          // padded bf16 row stride (136*2 = 272 B, 16B-aligned)
#define SCALE 0.125f

typedef __attribute__((ext_vector_type(8))) short bf16x8;
typedef __attribute__((ext_vector_type(4))) float f32x4;

__device__ __forceinline__ unsigned short f2bf(float x) {
    unsigned u = __builtin_bit_cast(unsigned, x);
    u += 0x7FFFu + ((u >> 16) & 1u);
    return (unsigned short)(u >> 16);
}
__device__ __forceinline__ float bf2f(unsigned short s) {
    unsigned u = ((unsigned)s) << 16;
    return __builtin_bit_cast(float, u);
}
__device__ __forceinline__ unsigned pack2(float a, float b) {
    return (unsigned)f2bf(a) | ((unsigned)f2bf(b) << 16);
}
// async global->LDS, 16B per lane; LDS dest = wave-uniform base + lane*16
__device__ __forceinline__ void gld_lds16(const uint4* g, uint4* l) {
    __builtin_amdgcn_global_load_lds(
        (const __attribute__((address_space(1))) unsigned int*)(g),
        (__attribute__((address_space(3))) unsigned int*)(l),
        16, 0, 0);
}

// ---------------- x (8192x1024 f32) -> bf16
__global__ __launch_bounds__(256) void conv_x(const float* __restrict__ in,
                                              unsigned short* __restrict__ ob) {
    size_t i = (size_t)blockIdx.x * 256 + threadIdx.x;   // one 8-elem chunk
    const float4* p = (const float4*)in + i * 2;
    float4 a = p[0], b = p[1];
    uint4 o;
    o.x = pack2(a.x, a.y); o.y = pack2(a.z, a.w);
    o.z = pack2(b.x, b.y); o.w = pack2(b.z, b.w);
    ((uint4*)ob)[i] = o;
}

// ---------------- W(q,k,v) (1024x1024 f32 each) -> WbT [3072][1024] bf16 (transposed)
__global__ __launch_bounds__(256) void conv_w(const float* __restrict__ Wq,
                                              const float* __restrict__ Wk,
                                              const float* __restrict__ Wv,
                                              unsigned short* __restrict__ WbT) {
    __shared__ float Ws[64][65];
    const int t = threadIdx.x;
    const int mi = blockIdx.x >> 8;
    const int rem = blockIdx.x & 255;
    const int k0 = (rem >> 4) * 64, n0 = (rem & 15) * 64;
    const float* W = mi == 0 ? Wq : (mi == 1 ? Wk : Wv);
    const int rr = t >> 4, c4 = (t & 15) * 4;
#pragma unroll
    for (int j = 0; j < 4; j++) {
        float4 v = *(const float4*)&W[(size_t)(k0 + rr + j * 16) * 1024 + n0 + c4];
        Ws[rr + j * 16][c4 + 0] = v.x; Ws[rr + j * 16][c4 + 1] = v.y;
        Ws[rr + j * 16][c4 + 2] = v.z; Ws[rr + j * 16][c4 + 3] = v.w;
    }
    __syncthreads();
    const int n = t >> 2;
    for (int cc = (t & 3); cc < 8; cc += 4) {
        unsigned short tmp[8];
#pragma unroll
        for (int j = 0; j < 8; j++) tmp[j] = f2bf(Ws[cc * 8 + j][n]);
        *(uint4*)&WbT[(size_t)(mi * 1024 + n0 + n) * 1024 + k0 + cc * 8] = *(uint4*)tmp;
    }
}

// ---------------- Eq/Ek (129x64 f32) -> bf16 [144][64], zero-padded rows
__global__ void conv_e(const float* __restrict__ Eq, const float* __restrict__ Ek,
                       unsigned short* __restrict__ Eqb, unsigned short* __restrict__ Ekb) {
    const int t = threadIdx.x;
    for (int i = t; i < 1152; i += 256) {
        int r = i >> 3, c8 = (i & 7) * 8;
        uint4 oq = {0, 0, 0, 0}, ok = {0, 0, 0, 0};
        if (r < NREL) {
            float4 a = *(const float4*)&Eq[r * 64 + c8];
            float4 b = *(const float4*)&Eq[r * 64 + c8 + 4];
            oq.x = pack2(a.x, a.y); oq.y = pack2(a.z, a.w);
            oq.z = pack2(b.x, b.y); oq.w = pack2(b.z, b.w);
            float4 c = *(const float4*)&Ek[r * 64 + c8];
            float4 d = *(const float4*)&Ek[r * 64 + c8 + 4];
            ok.x = pack2(c.x, c.y); ok.y = pack2(c.z, c.w);
            ok.z = pack2(d.x, d.y); ok.w = pack2(d.z, d.w);
        }
        ((uint4*)Eqb)[i] = oq;
        ((uint4*)Ekb)[i] = ok;
    }
}

// ---------------- ee[r] = dot(Eq[r], Ek[r])  (f32)
__global__ void ee_k(const float* __restrict__ Eq, const float* __restrict__ Ek,
                     float* __restrict__ ee) {
    int r = threadIdx.x;
    if (r < NREL) {
        float s = 0.f;
        for (int d = 0; d < HD; d++) s += Eq[r * HD + d] * Ek[r * HD + d];
        ee[r] = s;
    }
}

// ---------------- fused projection (m97 structure): [8192x3072] = xb @ W
// 128x128 tile, BK=64, single 32KB LDS buffer, global_load_lds w16, 2 barriers/K-step
__global__ __launch_bounds__(256) void proj_mfma(const unsigned short* __restrict__ xb,
                                                 const unsigned short* __restrict__ WbT,
                                                 unsigned short* __restrict__ Qb,
                                                 unsigned short* __restrict__ Kb,
                                                 unsigned short* __restrict__ Vb) {
    __shared__ uint4 smem[2176];             // A [0,1024) | B [1024,2048); cs aliases all 34816 B
    const int t = threadIdx.x;
    const int bm = blockIdx.x & 63;
    const int bn = blockIdx.x >> 6;          // 0..23
    const int m0 = bm * 128;
    const int n0g = bn * 128;
    const int w = t >> 6, lane = t & 63, ln = lane & 15, kg = lane >> 4;
    const int wm = w >> 1, wn = w & 1;
    const int lrow = lane >> 3;              // 0..7 within 8-row segment
    const int lcol = lane & 7;               // 16B chunk within 128B row slice

    f32x4 acc[4][4];
#pragma unroll
    for (int i = 0; i < 4; i++)
#pragma unroll
        for (int j = 0; j < 4; j++) acc[i][j] = (f32x4){0.f, 0.f, 0.f, 0.f};

    // per-wave staging descriptors: 4 A-segments + 4 B-segments of 8 rows x 128 B
    const uint4* gA[4]; const uint4* gB[4]; uint4* lA[4]; uint4* lB[4];
#pragma unroll
    for (int j = 0; j < 4; j++) {
        const int seg = w * 4 + j;           // 0..15
        gA[j] = (const uint4*)xb  + (size_t)(m0  + seg * 8 + lrow) * 128 + lcol;
        gB[j] = (const uint4*)WbT + (size_t)(n0g + seg * 8 + lrow) * 128 + lcol;
        lA[j] = smem + seg * 64;
        lB[j] = smem + 1024 + seg * 64;
    }

    for (int kt = 0; kt < 16; ++kt) {        // K-step: 8 chunks = 64 shorts
        __syncthreads();                     // prior readers done before overwrite
#pragma unroll
        for (int j = 0; j < 4; j++) {
            gld_lds16(gA[j] + kt * 8, lA[j]);
            gld_lds16(gB[j] + kt * 8, lB[j]);
        }
        __syncthreads();                     // drains vmcnt -> staged data visible
#pragma unroll
        for (int ks = 0; ks < 2; ks++) {
            bf16x8 af[4], bfr[4];
            const int ch = ks * 4 + kg;
#pragma unroll
            for (int i = 0; i < 4; i++) af[i]  = *(const bf16x8*)(smem + (wm * 64 + i * 16 + ln) * 8 + ch);
#pragma unroll
            for (int j = 0; j < 4; j++) bfr[j] = *(const bf16x8*)(smem + 1024 + (wn * 64 + j * 16 + ln) * 8 + ch);
#pragma unroll
            for (int i = 0; i < 4; i++)
#pragma unroll
                for (int j = 0; j < 4; j++)
                    acc[i][j] = __builtin_amdgcn_mfma_f32_16x16x32_bf16(af[i], bfr[j], acc[i][j], 0, 0, 0);
        }
    }
    __syncthreads();
    // epilogue: C tile to LDS (alias), then coalesced 256B-run stores
    short (*cs)[136] = (short(*)[136])smem;
#pragma unroll
    for (int i = 0; i < 4; i++)
#pragma unroll
        for (int j = 0; j < 4; j++)
#pragma unroll
            for (int reg = 0; reg < 4; reg++)
                cs[wm * 64 + i * 16 + kg * 4 + reg][wn * 64 + j * 16 + ln] = (short)f2bf(acc[i][j][reg]);
    __syncthreads();
    const int which = n0g >> 10;
    unsigned short* outp = which == 0 ? Qb : (which == 1 ? Kb : Vb);
    const int ncol0 = n0g & 1023;
#pragma unroll
    for (int j = 0; j < 8; j++) {
        int id = j * 256 + t;
        int r = id >> 4, c = id & 15;
        *((uint4*)(outp + (size_t)(m0 + r) * 1024 + ncol0) + c) = *((const uint4*)&cs[r][0] + c);
    }
}

// ---------------- qEe/kEb via MFMA: block = 64 g-rows, wave = 16 rows x 144 r-cols
__global__ __launch_bounds__(256) void qk_e_mfma(const unsigned short* __restrict__ Qb,
                                                 const unsigned short* __restrict__ Kb,
                                                 const unsigned short* __restrict__ Ekb,
                                                 const unsigned short* __restrict__ Eqb,
                                                 const float* __restrict__ ee,
                                                 unsigned short* __restrict__ qEe,
                                                 unsigned short* __restrict__ kEb) {
    __shared__ uint4 lds[3328];   // Qt 512 | Kt 512 | EkS 1152 | EqS 1152
    __shared__ float eeS[136];
    uint4* Qt = lds;
    uint4* Kt = lds + 512;
    uint4* EkS = lds + 1024;
    uint4* EqS = lds + 2176;
    const int t = threadIdx.x, w = t >> 6, lane = t & 63, ln = lane & 15, kg = lane >> 4;
    const int g0 = blockIdx.x * 64;

    {
        int r = t >> 2, cb = (t & 3) * 2;
        const uint4* qg = (const uint4*)Qb + (size_t)(g0 + r) * 8;
        const uint4* kgp = (const uint4*)Kb + (size_t)(g0 + r) * 8;
#pragma unroll
        for (int j = 0; j < 2; j++) {
            int c = cb + j;
            Qt[r * 8 + (c ^ (r & 7))] = qg[c];
            Kt[r * 8 + (c ^ (r & 7))] = kgp[c];
        }
    }
    for (int i = t; i < 1152; i += 256) {
        int r = i >> 3, c = i & 7;
        EkS[r * 8 + (c ^ (r & 7))] = ((const uint4*)Ekb)[i];
        EqS[r * 8 + (c ^ (r & 7))] = ((const uint4*)Eqb)[i];
    }
    if (t < NREL) eeS[t] = ee[t];
    __syncthreads();

    const int lx = ln & 7;
    // ---- phase 1: qE = Q @ Ek^T (+ee)
    {
        bf16x8 a0 = *(bf16x8*)&Qt[(w * 16 + ln) * 8 + (kg ^ lx)];
        bf16x8 a1 = *(bf16x8*)&Qt[(w * 16 + ln) * 8 + ((4 + kg) ^ lx)];
        f32x4 acc[9];
#pragma unroll
        for (int j = 0; j < 9; j++) acc[j] = (f32x4){0.f, 0.f, 0.f, 0.f};
#pragma unroll
        for (int j = 0; j < 9; j++) {
            acc[j] = __builtin_amdgcn_mfma_f32_16x16x32_bf16(a0, *(bf16x8*)&EkS[(j * 16 + ln) * 8 + (kg ^ lx)], acc[j], 0, 0, 0);
            acc[j] = __builtin_amdgcn_mfma_f32_16x16x32_bf16(a1, *(bf16x8*)&EkS[(j * 16 + ln) * 8 + ((4 + kg) ^ lx)], acc[j], 0, 0, 0);
        }
#pragma unroll
        for (int j = 0; j < 9; j++) {
            int r = j * 16 + ln;
            if (r <= 128) {
#pragma unroll
                for (int reg = 0; reg < 4; reg++) {
                    int g = g0 + w * 16 + kg * 4 + reg;
                    qEe[(size_t)g * ER + r] = f2bf(acc[j][reg] + eeS[r]);
                }
            }
        }
    }
    // ---- phase 2: kE = K @ Eq^T
    {
        bf16x8 a0 = *(bf16x8*)&Kt[(w * 16 + ln) * 8 + (kg ^ lx)];
        bf16x8 a1 = *(bf16x8*)&Kt[(w * 16 + ln) * 8 + ((4 + kg) ^ lx)];
        f32x4 acc[9];
#pragma unroll
        for (int j = 0; j < 9; j++) acc[j] = (f32x4){0.f, 0.f, 0.f, 0.f};
#pragma unroll
        for (int j = 0; j < 9; j++) {
            acc[j] = __builtin_amdgcn_mfma_f32_16x16x32_bf16(a0, *(bf16x8*)&EqS[(j * 16 + ln) * 8 + (kg ^ lx)], acc[j], 0, 0, 0);
            acc[j] = __builtin_amdgcn_mfma_f32_16x16x32_bf16(a1, *(bf16x8*)&EqS[(j * 16 + ln) * 8 + ((4 + kg) ^ lx)], acc[j], 0, 0, 0);
        }
#pragma unroll
        for (int j = 0; j < 9; j++) {
            int r = j * 16 + ln;
            if (r <= 128) {
#pragma unroll
                for (int reg = 0; reg < 4; reg++) {
                    int g = g0 + w * 16 + kg * 4 + reg;
                    kEb[(size_t)g * ER + r] = f2bf(acc[j][reg]);
                }
            }
        }
    }
}

// ---------------- attention (MFMA): block = (b,h,64 l-rows), 4 waves x 16 rows
__global__ __launch_bounds__(256) void attn_k(const unsigned short* __restrict__ Q,
                                              const unsigned short* __restrict__ K,
                                              const unsigned short* __restrict__ V,
                                              const unsigned short* __restrict__ qEg,
                                              const unsigned short* __restrict__ kEg,
                                              unsigned short* __restrict__ aRg,
                                              float* __restrict__ out) {
    __shared__ __align__(16) char un[18432];
    __shared__ short qEeS[64][ER];
    __shared__ short Pt[4][16][40];
    __shared__ short aRs[4][16][ER];
    __shared__ float invs[4][16];

    short (*Qsb)[64] = (short(*)[64])un;            // 8192
    short (*Kt)[72]  = (short(*)[72])un;            // 4608
    short (*Vtt)[40] = (short(*)[40])(un + 4608);   // 5120
    short (*kEt)[ER] = (short(*)[ER])(un + 9728);   // 8704

    const int t = threadIdx.x;
    const int lt = blockIdx.x & 7;
    const int bh = blockIdx.x >> 3;
    const int b = bh >> 4, h = bh & 15;
    const int bS = b * SEQ;
    const int l0 = lt * 64;
    const int w = t >> 6;
    const int lane = t & 63;
    const int ln = lane & 15;
    const int kg = lane >> 4;
    const int l0w = l0 + w * 16;

    for (int i = t; i < 512; i += 256) {
        int r = i >> 3, c8 = (i & 7) * 8;
        *(uint4*)&Qsb[r][c8] = *(const uint4*)&Q[(size_t)(bS + l0 + r) * 1024 + h * 64 + c8];
    }
    for (int i = t; i < 1088; i += 256) {
        int r = i / 17, c = i % 17;
        ((uint4*)&qEeS[r][0])[c] = ((const uint4*)&qEg[(size_t)((bS + l0 + r) * NH + h) * ER])[c];
    }
    for (int i = t; i < 4352; i += 256) ((unsigned*)aRs)[i] = 0u;
    __syncthreads();

    bf16x8 qf0 = *(bf16x8*)&Qsb[w * 16 + ln][kg * 8];
    bf16x8 qf1 = *(bf16x8*)&Qsb[w * 16 + ln][32 + kg * 8];

    f32x4 of[4];
#pragma unroll
    for (int nt = 0; nt < 4; nt++) of[nt] = (f32x4){0.f, 0.f, 0.f, 0.f};
    float rs[4]   = {0.f, 0.f, 0.f, 0.f};
    float s0[4]   = {0.f, 0.f, 0.f, 0.f};
    float s128[4] = {0.f, 0.f, 0.f, 0.f};

    for (int mt = 0; mt < 16; mt++) {
        const int m0 = mt * 32;
        __syncthreads();
        {
            int r = t >> 3, c8 = (t & 7) * 8;
            *(uint4*)&Kt[r][c8] = *(const uint4*)&K[(size_t)(bS + m0 + r) * 1024 + h * 64 + c8];
            uint4 vv = *(const uint4*)&V[(size_t)(bS + m0 + r) * 1024 + h * 64 + c8];
            short* vs = (short*)&vv;
#pragma unroll
            for (int j = 0; j < 8; j++) Vtt[c8 + j][r] = vs[j];
        }
        for (int i = t; i < 544; i += 256) {
            int r = i / 17, c = i % 17;
            ((uint4*)&kEt[r][0])[c] = ((const uint4*)&kEg[(size_t)((bS + m0 + r) * NH + h) * ER])[c];
        }
        __syncthreads();

#pragma unroll
        for (int sub = 0; sub < 2; sub++) {
            f32x4 acc = (f32x4){0.f, 0.f, 0.f, 0.f};
            acc = __builtin_amdgcn_mfma_f32_16x16x32_bf16(qf0, *(bf16x8*)&Kt[sub * 16 + ln][kg * 8], acc, 0, 0, 0);
            acc = __builtin_amdgcn_mfma_f32_16x16x32_bf16(qf1, *(bf16x8*)&Kt[sub * 16 + ln][32 + kg * 8], acc, 0, 0, 0);
            const int mloc = sub * 16 + ln;
            const int m = m0 + mloc;
#pragma unroll
            for (int reg = 0; reg < 4; reg++) {
                const int lr = kg * 4 + reg;
                const int dlt = (l0w + lr) - m;
                const int r = dlt < -64 ? 0 : (dlt > 64 ? 128 : dlt + 64);
                float lg = (acc[reg] + bf2f((unsigned short)qEeS[w * 16 + lr][r])
                                     + bf2f((unsigned short)kEt[mloc][r])) * SCALE;
                float p = __expf(lg);
                rs[reg] += p;
                if (dlt >= 64)       s128[reg] += p;
                else if (dlt <= -64) s0[reg]   += p;
                else                 aRs[w][lr][r] = (short)f2bf(p);
                Pt[w][lr][mloc] = (short)f2bf(p);
            }
        }
        asm volatile("" ::: "memory");
        bf16x8 pf = *(bf16x8*)&Pt[w][ln][kg * 8];
#pragma unroll
        for (int nt = 0; nt < 4; nt++) {
            of[nt] = __builtin_amdgcn_mfma_f32_16x16x32_bf16(pf, *(bf16x8*)&Vtt[nt * 16 + ln][kg * 8], of[nt], 0, 0, 0);
        }
    }

    __syncthreads();
#pragma unroll
    for (int reg = 0; reg < 4; reg++) {
        for (int off = 1; off <= 8; off <<= 1) {
            rs[reg]   += __shfl_xor(rs[reg], off);
            s0[reg]   += __shfl_xor(s0[reg], off);
            s128[reg] += __shfl_xor(s128[reg], off);
        }
    }
    float inv[4];
#pragma unroll
    for (int reg = 0; reg < 4; reg++) inv[reg] = 1.0f / rs[reg];

    if (ln == 0) {
#pragma unroll
        for (int reg = 0; reg < 4; reg++) {
            aRs[w][kg * 4 + reg][0]   = (short)f2bf(s0[reg]   * inv[reg]);
            aRs[w][kg * 4 + reg][128] = (short)f2bf(s128[reg] * inv[reg]);
            invs[w][kg * 4 + reg] = inv[reg];
        }
    }
    __syncthreads();
    {
        const int row = lane >> 2;
        const float sc = invs[w][row];
#pragma unroll
        for (int kk = 0; kk < 32; kk++) {
            int c = (lane & 3) * 32 + kk;
            if (c >= 1) aRs[w][row][c] = (short)f2bf(bf2f((unsigned short)aRs[w][row][c]) * sc);
        }
    }
#pragma unroll
    for (int nt = 0; nt < 4; nt++)
#pragma unroll
        for (int reg = 0; reg < 4; reg++) of[nt][reg] *= inv[reg];
    __syncthreads();

#pragma unroll
    for (int nt = 0; nt < 4; nt++)
#pragma unroll
        for (int reg = 0; reg < 4; reg++)
            out[(size_t)(bS + l0w + kg * 4 + reg) * 1024 + h * 64 + nt * 16 + ln] = of[nt][reg];

    for (int i = lane; i < 272; i += 64) {
        int r = i / 17, c = i % 17;
        ((uint4*)&aRg[(size_t)((bS + l0w + r) * NH + h) * ER])[c] = ((const uint4*)&aRs[w][r][0])[c];
    }
}

// ---------------- out += aRn @ Ev
__global__ __launch_bounds__(256) void rel_av(const unsigned short* __restrict__ aRg,
                                              const float* __restrict__ Ev,
                                              float* __restrict__ out) {
    __shared__ short EvT[64][ER];
    __shared__ short aRst[64][ER];
    const int t = threadIdx.x;
    const int g0 = blockIdx.x * 64;
    const int w = t >> 6, lane = t & 63, ln = lane & 15, kg = lane >> 4;

    for (int i = t; i < 2048; i += 256) {
        int r = i >> 4, c = (i & 15) << 2;
        float4 e = *(const float4*)&Ev[r * HD + c];
        EvT[c + 0][r] = (short)f2bf(e.x);
        EvT[c + 1][r] = (short)f2bf(e.y);
        EvT[c + 2][r] = (short)f2bf(e.z);
        EvT[c + 3][r] = (short)f2bf(e.w);
    }
    for (int i = t; i < 1088; i += 256) {
        int r = i / 17, c = i % 17;
        ((uint4*)&aRst[r][0])[c] = ((const uint4*)&aRg[(size_t)(g0 + r) * ER])[c];
    }
    __syncthreads();

    f32x4 of[4];
#pragma unroll
    for (int nt = 0; nt < 4; nt++) of[nt] = (f32x4){0.f, 0.f, 0.f, 0.f};
#pragma unroll
    for (int nt = 0; nt < 4; nt++)
#pragma unroll
        for (int ks = 0; ks < 4; ks++)
            of[nt] = __builtin_amdgcn_mfma_f32_16x16x32_bf16(*(bf16x8*)&aRst[w * 16 + ln][ks * 32 + kg * 8],
                                                             *(bf16x8*)&EvT[nt * 16 + ln][ks * 32 + kg * 8],
                                                             of[nt], 0, 0, 0);
#pragma unroll
    for (int nt = 0; nt < 4; nt++) {
        float ev128 = Ev[128 * HD + nt * 16 + ln];
#pragma unroll
        for (int reg = 0; reg < 4; reg++) {
            int lr = w * 16 + kg * 4 + reg;
            float a128 = bf2f((unsigned short)aRst[lr][128]);
            out[(size_t)(g0 + lr) * HD + nt * 16 + ln] += of[nt][reg] + a128 * ev128;
        }
    }
}

extern "C" void kernel_launch(void* const* d_in, const int* in_sizes, int n_in,
                              void* d_out, int out_size, void* d_ws, size_t ws_size,
                              hipStream_t stream) {
    const float* x  = (const float*)d_in[0];
    const float* Wq = (const float*)d_in[1];
    const float* Wk = (const float*)d_in[2];
    const float* Wv = (const float*)d_in[3];
    const float* Eq = (const float*)d_in[4];
    const float* Ek = (const float*)d_in[5];
    const float* Ev = (const float*)d_in[6];
    float* out = (float*)d_out;
    char* ws = (char*)d_ws;

    unsigned short* Qb  = (unsigned short*)(ws);                    // 16,777,216
    unsigned short* Kb  = (unsigned short*)(ws + 16777216ull);
    unsigned short* Vb  = (unsigned short*)(ws + 33554432ull);
    unsigned short* xb  = (unsigned short*)(ws + 50331648ull);      // 16,777,216
    unsigned short* WbT = (unsigned short*)(ws + 67108864ull);      // 6,291,456
    unsigned short* Ekb = (unsigned short*)(ws + 73400320ull);      // 18,432
    unsigned short* Eqb = (unsigned short*)(ws + 73418752ull);      // 18,432
    float*          ee  = (float*)(ws + 73437184ull);               // 576
    unsigned short* qEe = (unsigned short*)(ws + 73437760ull);      // 35,651,584
    unsigned short* kEb = (unsigned short*)(ws + 109089344ull);     // 35,651,584
    unsigned short* aRg = (unsigned short*)(ws + 144740928ull);     // 35,651,584 (end ~180.4 MB)

    conv_x<<<4096, 256, 0, stream>>>(x, xb);
    conv_w<<<768, 256, 0, stream>>>(Wq, Wk, Wv, WbT);
    conv_e<<<1, 256, 0, stream>>>(Eq, Ek, Eqb, Ekb);
    ee_k<<<1, 256, 0, stream>>>(Eq, Ek, ee);
    proj_mfma<<<1536, 256, 0, stream>>>(xb, WbT, Qb, Kb, Vb);
    qk_e_mfma<<<2048, 256, 0, stream>>>(Qb, Kb, Ekb, Eqb, ee, qEe, kEb);
    attn_k<<<2048, 256, 0, stream>>>(Qb, Kb, Vb, qEe, kEb, aRg, out);
    rel_av<<<2048, 256, 0, stream>>>(aRg, Ev, out);
}

// Round 5
// 261.956 us; speedup vs baseline: 8.9843x; 1.3638x over previous
//
#include <hip/hip_runtime.h>

#define SEQ 512
#define NH 16
#define HD 64
#define NREL 129
#define ER 136          // padded bf16 row stride (136*2 = 272 B, 16B-aligned)
#define SCALE 0.125f

typedef __attribute__((ext_vector_type(8))) short bf16x8;
typedef __attribute__((ext_vector_type(4))) float f32x4;

__device__ __forceinline__ unsigned short f2bf(float x) {
    unsigned u = __builtin_bit_cast(unsigned, x);
    u += 0x7FFFu + ((u >> 16) & 1u);
    return (unsigned short)(u >> 16);
}
__device__ __forceinline__ float bf2f(unsigned short s) {
    unsigned u = ((unsigned)s) << 16;
    return __builtin_bit_cast(float, u);
}
__device__ __forceinline__ unsigned pack2(float a, float b) {
    return (unsigned)f2bf(a) | ((unsigned)f2bf(b) << 16);
}
// async global->LDS, 16B per lane; LDS dest = wave-uniform base + lane*16
__device__ __forceinline__ void gld_lds16(const uint4* g, uint4* l) {
    __builtin_amdgcn_global_load_lds(
        (const __attribute__((address_space(1))) unsigned int*)(g),
        (__attribute__((address_space(3))) unsigned int*)(l),
        16, 0, 0);
}

// ---------------- x (8192x1024 f32) -> bf16
__global__ __launch_bounds__(256) void conv_x(const float* __restrict__ in,
                                              unsigned short* __restrict__ ob) {
    size_t i = (size_t)blockIdx.x * 256 + threadIdx.x;   // one 8-elem chunk
    const float4* p = (const float4*)in + i * 2;
    float4 a = p[0], b = p[1];
    uint4 o;
    o.x = pack2(a.x, a.y); o.y = pack2(a.z, a.w);
    o.z = pack2(b.x, b.y); o.w = pack2(b.z, b.w);
    ((uint4*)ob)[i] = o;
}

// ---------------- W(q,k,v) (1024x1024 f32 each) -> WbT [3072][1024] bf16 (transposed)
__global__ __launch_bounds__(256) void conv_w(const float* __restrict__ Wq,
                                              const float* __restrict__ Wk,
                                              const float* __restrict__ Wv,
                                              unsigned short* __restrict__ WbT) {
    __shared__ float Ws[64][65];
    const int t = threadIdx.x;
    const int mi = blockIdx.x >> 8;
    const int rem = blockIdx.x & 255;
    const int k0 = (rem >> 4) * 64, n0 = (rem & 15) * 64;
    const float* W = mi == 0 ? Wq : (mi == 1 ? Wk : Wv);
    const int rr = t >> 4, c4 = (t & 15) * 4;
#pragma unroll
    for (int j = 0; j < 4; j++) {
        float4 v = *(const float4*)&W[(size_t)(k0 + rr + j * 16) * 1024 + n0 + c4];
        Ws[rr + j * 16][c4 + 0] = v.x; Ws[rr + j * 16][c4 + 1] = v.y;
        Ws[rr + j * 16][c4 + 2] = v.z; Ws[rr + j * 16][c4 + 3] = v.w;
    }
    __syncthreads();
    const int n = t >> 2;
    for (int cc = (t & 3); cc < 8; cc += 4) {
        unsigned short tmp[8];
#pragma unroll
        for (int j = 0; j < 8; j++) tmp[j] = f2bf(Ws[cc * 8 + j][n]);
        *(uint4*)&WbT[(size_t)(mi * 1024 + n0 + n) * 1024 + k0 + cc * 8] = *(uint4*)tmp;
    }
}

// ---------------- Eq/Ek (129x64 f32) -> bf16 [144][64], zero-padded rows
__global__ void conv_e(const float* __restrict__ Eq, const float* __restrict__ Ek,
                       unsigned short* __restrict__ Eqb, unsigned short* __restrict__ Ekb) {
    const int t = threadIdx.x;
    for (int i = t; i < 1152; i += 256) {
        int r = i >> 3, c8 = (i & 7) * 8;
        uint4 oq = {0, 0, 0, 0}, ok = {0, 0, 0, 0};
        if (r < NREL) {
            float4 a = *(const float4*)&Eq[r * 64 + c8];
            float4 b = *(const float4*)&Eq[r * 64 + c8 + 4];
            oq.x = pack2(a.x, a.y); oq.y = pack2(a.z, a.w);
            oq.z = pack2(b.x, b.y); oq.w = pack2(b.z, b.w);
            float4 c = *(const float4*)&Ek[r * 64 + c8];
            float4 d = *(const float4*)&Ek[r * 64 + c8 + 4];
            ok.x = pack2(c.x, c.y); ok.y = pack2(c.z, c.w);
            ok.z = pack2(d.x, d.y); ok.w = pack2(d.z, d.w);
        }
        ((uint4*)Eqb)[i] = oq;
        ((uint4*)Ekb)[i] = ok;
    }
}

// ---------------- ee[r] = dot(Eq[r], Ek[r])  (f32)
__global__ void ee_k(const float* __restrict__ Eq, const float* __restrict__ Ek,
                     float* __restrict__ ee) {
    int r = threadIdx.x;
    if (r < NREL) {
        float s = 0.f;
        for (int d = 0; d < HD; d++) s += Eq[r * HD + d] * Ek[r * HD + d];
        ee[r] = s;
    }
}

// ---------------- fused projection (m97 structure): [8192x3072] = xb @ W
__global__ __launch_bounds__(256) void proj_mfma(const unsigned short* __restrict__ xb,
                                                 const unsigned short* __restrict__ WbT,
                                                 unsigned short* __restrict__ Qb,
                                                 unsigned short* __restrict__ Kb,
                                                 unsigned short* __restrict__ Vb) {
    __shared__ uint4 smem[2176];
    const int t = threadIdx.x;
    const int bm = blockIdx.x & 63;
    const int bn = blockIdx.x >> 6;
    const int m0 = bm * 128;
    const int n0g = bn * 128;
    const int w = t >> 6, lane = t & 63, ln = lane & 15, kg = lane >> 4;
    const int wm = w >> 1, wn = w & 1;
    const int lrow = lane >> 3;
    const int lcol = lane & 7;

    f32x4 acc[4][4];
#pragma unroll
    for (int i = 0; i < 4; i++)
#pragma unroll
        for (int j = 0; j < 4; j++) acc[i][j] = (f32x4){0.f, 0.f, 0.f, 0.f};

    const uint4* gA[4]; const uint4* gB[4]; uint4* lA[4]; uint4* lB[4];
#pragma unroll
    for (int j = 0; j < 4; j++) {
        const int seg = w * 4 + j;
        gA[j] = (const uint4*)xb  + (size_t)(m0  + seg * 8 + lrow) * 128 + lcol;
        gB[j] = (const uint4*)WbT + (size_t)(n0g + seg * 8 + lrow) * 128 + lcol;
        lA[j] = smem + seg * 64;
        lB[j] = smem + 1024 + seg * 64;
    }

    for (int kt = 0; kt < 16; ++kt) {
        __syncthreads();
#pragma unroll
        for (int j = 0; j < 4; j++) {
            gld_lds16(gA[j] + kt * 8, lA[j]);
            gld_lds16(gB[j] + kt * 8, lB[j]);
        }
        __syncthreads();
#pragma unroll
        for (int ks = 0; ks < 2; ks++) {
            bf16x8 af[4], bfr[4];
            const int ch = ks * 4 + kg;
#pragma unroll
            for (int i = 0; i < 4; i++) af[i]  = *(const bf16x8*)(smem + (wm * 64 + i * 16 + ln) * 8 + ch);
#pragma unroll
            for (int j = 0; j < 4; j++) bfr[j] = *(const bf16x8*)(smem + 1024 + (wn * 64 + j * 16 + ln) * 8 + ch);
#pragma unroll
            for (int i = 0; i < 4; i++)
#pragma unroll
                for (int j = 0; j < 4; j++)
                    acc[i][j] = __builtin_amdgcn_mfma_f32_16x16x32_bf16(af[i], bfr[j], acc[i][j], 0, 0, 0);
        }
    }
    __syncthreads();
    short (*cs)[136] = (short(*)[136])smem;
#pragma unroll
    for (int i = 0; i < 4; i++)
#pragma unroll
        for (int j = 0; j < 4; j++)
#pragma unroll
            for (int reg = 0; reg < 4; reg++)
                cs[wm * 64 + i * 16 + kg * 4 + reg][wn * 64 + j * 16 + ln] = (short)f2bf(acc[i][j][reg]);
    __syncthreads();
    const int which = n0g >> 10;
    unsigned short* outp = which == 0 ? Qb : (which == 1 ? Kb : Vb);
    const int ncol0 = n0g & 1023;
#pragma unroll
    for (int j = 0; j < 8; j++) {
        int id = j * 256 + t;
        int r = id >> 4, c = id & 15;
        *((uint4*)(outp + (size_t)(m0 + r) * 1024 + ncol0) + c) = *((const uint4*)&cs[r][0] + c);
    }
}

// ---------------- qEe/kEb via MFMA
__global__ __launch_bounds__(256) void qk_e_mfma(const unsigned short* __restrict__ Qb,
                                                 const unsigned short* __restrict__ Kb,
                                                 const unsigned short* __restrict__ Ekb,
                                                 const unsigned short* __restrict__ Eqb,
                                                 const float* __restrict__ ee,
                                                 unsigned short* __restrict__ qEe,
                                                 unsigned short* __restrict__ kEb) {
    __shared__ uint4 lds[3328];
    __shared__ float eeS[136];
    uint4* Qt = lds;
    uint4* Kt = lds + 512;
    uint4* EkS = lds + 1024;
    uint4* EqS = lds + 2176;
    const int t = threadIdx.x, w = t >> 6, lane = t & 63, ln = lane & 15, kg = lane >> 4;
    const int g0 = blockIdx.x * 64;

    {
        int r = t >> 2, cb = (t & 3) * 2;
        const uint4* qg = (const uint4*)Qb + (size_t)(g0 + r) * 8;
        const uint4* kgp = (const uint4*)Kb + (size_t)(g0 + r) * 8;
#pragma unroll
        for (int j = 0; j < 2; j++) {
            int c = cb + j;
            Qt[r * 8 + (c ^ (r & 7))] = qg[c];
            Kt[r * 8 + (c ^ (r & 7))] = kgp[c];
        }
    }
    for (int i = t; i < 1152; i += 256) {
        int r = i >> 3, c = i & 7;
        EkS[r * 8 + (c ^ (r & 7))] = ((const uint4*)Ekb)[i];
        EqS[r * 8 + (c ^ (r & 7))] = ((const uint4*)Eqb)[i];
    }
    if (t < NREL) eeS[t] = ee[t];
    __syncthreads();

    const int lx = ln & 7;
    {
        bf16x8 a0 = *(bf16x8*)&Qt[(w * 16 + ln) * 8 + (kg ^ lx)];
        bf16x8 a1 = *(bf16x8*)&Qt[(w * 16 + ln) * 8 + ((4 + kg) ^ lx)];
        f32x4 acc[9];
#pragma unroll
        for (int j = 0; j < 9; j++) acc[j] = (f32x4){0.f, 0.f, 0.f, 0.f};
#pragma unroll
        for (int j = 0; j < 9; j++) {
            acc[j] = __builtin_amdgcn_mfma_f32_16x16x32_bf16(a0, *(bf16x8*)&EkS[(j * 16 + ln) * 8 + (kg ^ lx)], acc[j], 0, 0, 0);
            acc[j] = __builtin_amdgcn_mfma_f32_16x16x32_bf16(a1, *(bf16x8*)&EkS[(j * 16 + ln) * 8 + ((4 + kg) ^ lx)], acc[j], 0, 0, 0);
        }
#pragma unroll
        for (int j = 0; j < 9; j++) {
            int r = j * 16 + ln;
            if (r <= 128) {
#pragma unroll
                for (int reg = 0; reg < 4; reg++) {
                    int g = g0 + w * 16 + kg * 4 + reg;
                    qEe[(size_t)g * ER + r] = f2bf(acc[j][reg] + eeS[r]);
                }
            }
        }
    }
    {
        bf16x8 a0 = *(bf16x8*)&Kt[(w * 16 + ln) * 8 + (kg ^ lx)];
        bf16x8 a1 = *(bf16x8*)&Kt[(w * 16 + ln) * 8 + ((4 + kg) ^ lx)];
        f32x4 acc[9];
#pragma unroll
        for (int j = 0; j < 9; j++) acc[j] = (f32x4){0.f, 0.f, 0.f, 0.f};
#pragma unroll
        for (int j = 0; j < 9; j++) {
            acc[j] = __builtin_amdgcn_mfma_f32_16x16x32_bf16(a0, *(bf16x8*)&EqS[(j * 16 + ln) * 8 + (kg ^ lx)], acc[j], 0, 0, 0);
            acc[j] = __builtin_amdgcn_mfma_f32_16x16x32_bf16(a1, *(bf16x8*)&EqS[(j * 16 + ln) * 8 + ((4 + kg) ^ lx)], acc[j], 0, 0, 0);
        }
#pragma unroll
        for (int j = 0; j < 9; j++) {
            int r = j * 16 + ln;
            if (r <= 128) {
#pragma unroll
                for (int reg = 0; reg < 4; reg++) {
                    int g = g0 + w * 16 + kg * 4 + reg;
                    kEb[(size_t)g * ER + r] = f2bf(acc[j][reg]);
                }
            }
        }
    }
}

// ---------------- attention (MFMA, T14 async-stage, fused rel_av)
// block = (b,h,64 l-rows), 4 waves x 16 rows
__global__ __launch_bounds__(256) void attn_k(const unsigned short* __restrict__ Q,
                                              const unsigned short* __restrict__ K,
                                              const unsigned short* __restrict__ V,
                                              const unsigned short* __restrict__ qEg,
                                              const unsigned short* __restrict__ kEg,
                                              const float* __restrict__ Ev,
                                              float* __restrict__ out) {
    __shared__ __align__(16) char un[18432];        // Qsb | (Kt,Vtt,kEt) | epilogue EvT
    __shared__ short qEeS[64][ER];                  // 17408
    __shared__ short Pt[4][16][40];                 // 5120
    __shared__ short aRs[4][16][ER];                // 17408
    __shared__ float invs[4][16];                   // 256

    short (*Qsb)[64] = (short(*)[64])un;            // 8192 (prologue)
    short (*Kt)[72]  = (short(*)[72])un;            // 4608
    short* Vtt       = (short*)(un + 4608);         // [64][40] chunk-swizzled, 5120
    short (*kEt)[ER] = (short(*)[ER])(un + 9728);   // 8704
    short (*EvT)[ER] = (short(*)[ER])un;            // epilogue overlay [64][136] = 17408

    const int t = threadIdx.x;
    // supergroup swizzle: 8 same-bh blocks -> same XCD, adjacent in dispatch
    const int g = blockIdx.x;
    const int lt = (g >> 3) & 7;
    const int bh = ((g >> 6) << 3) | (g & 7);
    const int b = bh >> 4, h = bh & 15;
    const int bS = b * SEQ;
    const int l0 = lt * 64;
    const int w = t >> 6;
    const int lane = t & 63;
    const int ln = lane & 15;
    const int kg = lane >> 4;
    const int l0w = l0 + w * 16;

    // ---- startup staging
    for (int i = t; i < 512; i += 256) {
        int r = i >> 3, c8 = (i & 7) * 8;
        *(uint4*)&Qsb[r][c8] = *(const uint4*)&Q[(size_t)(bS + l0 + r) * 1024 + h * 64 + c8];
    }
    for (int i = t; i < 1088; i += 256) {
        int r = i / 17, c = i % 17;
        ((uint4*)&qEeS[r][0])[c] = ((const uint4*)&qEg[(size_t)((bS + l0 + r) * NH + h) * ER])[c];
    }
    for (int i = t; i < 4352; i += 256) ((unsigned*)aRs)[i] = 0u;
    __syncthreads();

    bf16x8 qf0 = *(bf16x8*)&Qsb[w * 16 + ln][kg * 8];
    bf16x8 qf1 = *(bf16x8*)&Qsb[w * 16 + ln][32 + kg * 8];

    // ---- T14 staging descriptors
    const int sr = t >> 3;              // K/V m-row 0..31
    const int sc8 = (t & 7) * 8;        // d base
    const unsigned short* Kg0 = K + (size_t)(bS + sr) * 1024 + h * 64 + sc8;
    const unsigned short* Vg0 = V + (size_t)(bS + sr) * 1024 + h * 64 + sc8;
    const int r0 = t / 17,          c0 = t % 17;
    const int r1 = (t + 256) / 17,  c1 = (t + 256) % 17;
    const int r2 = (t + 512) / 17,  c2 = (t + 512) % 17;   // only t<32
    const unsigned short* kE0 = kEg + ((size_t)(bS + r0) * NH + h) * ER;
    const unsigned short* kE1 = kEg + ((size_t)(bS + r1) * NH + h) * ER;
    const unsigned short* kE2 = kEg + ((size_t)(bS + r2) * NH + h) * ER;

    uint4 kv, vv, ke0, ke1, ke2;
    kv  = *(const uint4*)(Kg0);
    vv  = *(const uint4*)(Vg0);
    ke0 = ((const uint4*)kE0)[c0];
    ke1 = ((const uint4*)kE1)[c1];
    if (t < 32) ke2 = ((const uint4*)kE2)[c2];

    f32x4 of[4];
#pragma unroll
    for (int nt = 0; nt < 4; nt++) of[nt] = (f32x4){0.f, 0.f, 0.f, 0.f};
    float rs[4]   = {0.f, 0.f, 0.f, 0.f};
    float s0[4]   = {0.f, 0.f, 0.f, 0.f};
    float s128[4] = {0.f, 0.f, 0.f, 0.f};

    const int vkey = (t & 7) & 3;       // = ((d>>3)&3) for this thread's d-chunk
    for (int mt = 0; mt < 16; mt++) {
        const int m0 = mt * 32;
        __syncthreads();                // prior readers done
        // write staged regs -> LDS
        *(uint4*)&Kt[sr][sc8] = kv;
        {
            const short* vs = (const short*)&vv;
#pragma unroll
            for (int j = 0; j < 8; j++) {
                const int d = sc8 + j;
                Vtt[d * 40 + ((((sr >> 3) ^ vkey)) << 3) + (sr & 7)] = vs[j];
            }
        }
        ((uint4*)&kEt[r0][0])[c0] = ke0;
        ((uint4*)&kEt[r1][0])[c1] = ke1;
        if (t < 32) ((uint4*)&kEt[r2][0])[c2] = ke2;
        // issue next-tile loads (latency hides under this tile's compute)
        if (mt < 15) {
            const size_t koff = (size_t)(mt + 1) * 32 * 1024;
            const size_t eoff = (size_t)(mt + 1) * 32 * NH * ER;
            kv  = *(const uint4*)(Kg0 + koff);
            vv  = *(const uint4*)(Vg0 + koff);
            ke0 = ((const uint4*)(kE0 + eoff))[c0];
            ke1 = ((const uint4*)(kE1 + eoff))[c1];
            if (t < 32) ke2 = ((const uint4*)(kE2 + eoff))[c2];
        }
        __syncthreads();                // staged LDS visible

        // QK^T + bias + exp; write P (bf16) + aR band
#pragma unroll
        for (int sub = 0; sub < 2; sub++) {
            f32x4 acc = (f32x4){0.f, 0.f, 0.f, 0.f};
            acc = __builtin_amdgcn_mfma_f32_16x16x32_bf16(qf0, *(bf16x8*)&Kt[sub * 16 + ln][kg * 8], acc, 0, 0, 0);
            acc = __builtin_amdgcn_mfma_f32_16x16x32_bf16(qf1, *(bf16x8*)&Kt[sub * 16 + ln][32 + kg * 8], acc, 0, 0, 0);
            const int mloc = sub * 16 + ln;
            const int m = m0 + mloc;
#pragma unroll
            for (int reg = 0; reg < 4; reg++) {
                const int lr = kg * 4 + reg;
                const int dlt = (l0w + lr) - m;
                const int r = dlt < -64 ? 0 : (dlt > 64 ? 128 : dlt + 64);
                float lg = (acc[reg] + bf2f((unsigned short)qEeS[w * 16 + lr][r])
                                     + bf2f((unsigned short)kEt[mloc][r])) * SCALE;
                float p = __expf(lg);
                rs[reg] += p;
                if (dlt >= 64)       s128[reg] += p;
                else if (dlt <= -64) s0[reg]   += p;
                else                 aRs[w][lr][r] = (short)f2bf(p);
                Pt[w][lr][mloc] = (short)f2bf(p);
            }
        }
        asm volatile("" ::: "memory");
        // PV (swizzled Vtt frag read)
        bf16x8 pf = *(bf16x8*)&Pt[w][ln][kg * 8];
#pragma unroll
        for (int nt = 0; nt < 4; nt++) {
            const int d = nt * 16 + ln;
            const bf16x8 vf = *(const bf16x8*)&Vtt[d * 40 + ((kg ^ ((d >> 3) & 3)) << 3)];
            of[nt] = __builtin_amdgcn_mfma_f32_16x16x32_bf16(pf, vf, of[nt], 0, 0, 0);
        }
    }

    __syncthreads();                    // un free from here
    // row reductions across the 16 lanes sharing rows
#pragma unroll
    for (int reg = 0; reg < 4; reg++) {
        for (int off = 1; off <= 8; off <<= 1) {
            rs[reg]   += __shfl_xor(rs[reg], off);
            s0[reg]   += __shfl_xor(s0[reg], off);
            s128[reg] += __shfl_xor(s128[reg], off);
        }
    }
    float inv[4];
#pragma unroll
    for (int reg = 0; reg < 4; reg++) inv[reg] = 1.0f / rs[reg];

    if (ln == 0) {
#pragma unroll
        for (int reg = 0; reg < 4; reg++) {
            aRs[w][kg * 4 + reg][0]   = (short)f2bf(s0[reg]   * inv[reg]);
            aRs[w][kg * 4 + reg][128] = (short)f2bf(s128[reg] * inv[reg]);
            invs[w][kg * 4 + reg] = inv[reg];
        }
    }
    // stage EvT (transposed Ev) into the dead K/V/kE region
    for (int i = t; i < 8256; i += 256) {      // 129*64
        int r = i >> 6, d = i & 63;
        EvT[d][r] = (short)f2bf(Ev[i]);
    }
    __syncthreads();
    // normalize band cols 1..127
    {
        const int row = lane >> 2;
        const float sc = invs[w][row];
#pragma unroll
        for (int kk = 0; kk < 32; kk++) {
            int c = (lane & 3) * 32 + kk;
            if (c >= 1) aRs[w][row][c] = (short)f2bf(bf2f((unsigned short)aRs[w][row][c]) * sc);
        }
    }
    // normalize PV accumulators
#pragma unroll
    for (int nt = 0; nt < 4; nt++)
#pragma unroll
        for (int reg = 0; reg < 4; reg++) of[nt][reg] *= inv[reg];
    __syncthreads();

    // fused rel_av: o2 = aRn @ EvT  (cols 0..127), plus col-128 edge
    f32x4 o2[4];
#pragma unroll
    for (int nt = 0; nt < 4; nt++) o2[nt] = (f32x4){0.f, 0.f, 0.f, 0.f};
#pragma unroll
    for (int nt = 0; nt < 4; nt++)
#pragma unroll
        for (int ks = 0; ks < 4; ks++)
            o2[nt] = __builtin_amdgcn_mfma_f32_16x16x32_bf16(*(bf16x8*)&aRs[w][ln][ks * 32 + kg * 8],
                                                             *(bf16x8*)&EvT[nt * 16 + ln][ks * 32 + kg * 8],
                                                             o2[nt], 0, 0, 0);
#pragma unroll
    for (int nt = 0; nt < 4; nt++) {
        const float e128 = bf2f((unsigned short)EvT[nt * 16 + ln][128]);
#pragma unroll
        for (int reg = 0; reg < 4; reg++) {
            const int lr = kg * 4 + reg;
            const float a128 = bf2f((unsigned short)aRs[w][lr][128]);
            out[(size_t)(bS + l0w + lr) * 1024 + h * 64 + nt * 16 + ln] =
                of[nt][reg] + o2[nt][reg] + a128 * e128;
        }
    }
}

extern "C" void kernel_launch(void* const* d_in, const int* in_sizes, int n_in,
                              void* d_out, int out_size, void* d_ws, size_t ws_size,
                              hipStream_t stream) {
    const float* x  = (const float*)d_in[0];
    const float* Wq = (const float*)d_in[1];
    const float* Wk = (const float*)d_in[2];
    const float* Wv = (const float*)d_in[3];
    const float* Eq = (const float*)d_in[4];
    const float* Ek = (const float*)d_in[5];
    const float* Ev = (const float*)d_in[6];
    float* out = (float*)d_out;
    char* ws = (char*)d_ws;

    unsigned short* Qb  = (unsigned short*)(ws);                    // 16,777,216
    unsigned short* Kb  = (unsigned short*)(ws + 16777216ull);
    unsigned short* Vb  = (unsigned short*)(ws + 33554432ull);
    unsigned short* xb  = (unsigned short*)(ws + 50331648ull);      // 16,777,216
    unsigned short* WbT = (unsigned short*)(ws + 67108864ull);      // 6,291,456
    unsigned short* Ekb = (unsigned short*)(ws + 73400320ull);      // 18,432
    unsigned short* Eqb = (unsigned short*)(ws + 73418752ull);      // 18,432
    float*          ee  = (float*)(ws + 73437184ull);               // 576
    unsigned short* qEe = (unsigned short*)(ws + 73437760ull);      // 35,651,584
    unsigned short* kEb = (unsigned short*)(ws + 109089344ull);     // 35,651,584 (~144.7 MB)

    conv_x<<<4096, 256, 0, stream>>>(x, xb);
    conv_w<<<768, 256, 0, stream>>>(Wq, Wk, Wv, WbT);
    conv_e<<<1, 256, 0, stream>>>(Eq, Ek, Eqb, Ekb);
    ee_k<<<1, 256, 0, stream>>>(Eq, Ek, ee);
    proj_mfma<<<1536, 256, 0, stream>>>(xb, WbT, Qb, Kb, Vb);
    qk_e_mfma<<<2048, 256, 0, stream>>>(Qb, Kb, Ekb, Eqb, ee, qEe, kEb);
    attn_k<<<2048, 256, 0, stream>>>(Qb, Kb, Vb, qEe, kEb, Ev, out);
}

// Round 6
// 248.028 us; speedup vs baseline: 9.4888x; 1.0562x over previous
//
#include <hip/hip_runtime.h>

#define SEQ 512
#define NH 16
#define HD 64
#define NREL 129
#define ER 136          // padded bf16 row stride (136*2 = 272 B, 16B-aligned)
#define SCALE 0.125f

typedef __attribute__((ext_vector_type(8))) short bf16x8;
typedef __attribute__((ext_vector_type(4))) float f32x4;

__device__ __forceinline__ unsigned short f2bf(float x) {
    unsigned u = __builtin_bit_cast(unsigned, x);
    u += 0x7FFFu + ((u >> 16) & 1u);
    return (unsigned short)(u >> 16);
}
__device__ __forceinline__ float bf2f(unsigned short s) {
    unsigned u = ((unsigned)s) << 16;
    return __builtin_bit_cast(float, u);
}
__device__ __forceinline__ unsigned pack2(float a, float b) {
    return (unsigned)f2bf(a) | ((unsigned)f2bf(b) << 16);
}
// async global->LDS, 16B per lane; LDS dest = wave-uniform base + lane*16
__device__ __forceinline__ void gld_lds16(const uint4* g, uint4* l) {
    __builtin_amdgcn_global_load_lds(
        (const __attribute__((address_space(1))) unsigned int*)(g),
        (__attribute__((address_space(3))) unsigned int*)(l),
        16, 0, 0);
}

// ---------------- x (8192x1024 f32) -> bf16
__global__ __launch_bounds__(256) void conv_x(const float* __restrict__ in,
                                              unsigned short* __restrict__ ob) {
    size_t i = (size_t)blockIdx.x * 256 + threadIdx.x;   // one 8-elem chunk
    const float4* p = (const float4*)in + i * 2;
    float4 a = p[0], b = p[1];
    uint4 o;
    o.x = pack2(a.x, a.y); o.y = pack2(a.z, a.w);
    o.z = pack2(b.x, b.y); o.w = pack2(b.z, b.w);
    ((uint4*)ob)[i] = o;
}

// ---------------- W(q,k,v) (1024x1024 f32 each) -> WbT [3072][1024] bf16 (transposed)
__global__ __launch_bounds__(256) void conv_w(const float* __restrict__ Wq,
                                              const float* __restrict__ Wk,
                                              const float* __restrict__ Wv,
                                              unsigned short* __restrict__ WbT) {
    __shared__ float Ws[64][65];
    const int t = threadIdx.x;
    const int mi = blockIdx.x >> 8;
    const int rem = blockIdx.x & 255;
    const int k0 = (rem >> 4) * 64, n0 = (rem & 15) * 64;
    const float* W = mi == 0 ? Wq : (mi == 1 ? Wk : Wv);
    const int rr = t >> 4, c4 = (t & 15) * 4;
#pragma unroll
    for (int j = 0; j < 4; j++) {
        float4 v = *(const float4*)&W[(size_t)(k0 + rr + j * 16) * 1024 + n0 + c4];
        Ws[rr + j * 16][c4 + 0] = v.x; Ws[rr + j * 16][c4 + 1] = v.y;
        Ws[rr + j * 16][c4 + 2] = v.z; Ws[rr + j * 16][c4 + 3] = v.w;
    }
    __syncthreads();
    const int n = t >> 2;
    for (int cc = (t & 3); cc < 8; cc += 4) {
        unsigned short tmp[8];
#pragma unroll
        for (int j = 0; j < 8; j++) tmp[j] = f2bf(Ws[cc * 8 + j][n]);
        *(uint4*)&WbT[(size_t)(mi * 1024 + n0 + n) * 1024 + k0 + cc * 8] = *(uint4*)tmp;
    }
}

// ---------------- Eq/Ek (129x64 f32) -> bf16 [144][64], zero-padded rows
__global__ void conv_e(const float* __restrict__ Eq, const float* __restrict__ Ek,
                       unsigned short* __restrict__ Eqb, unsigned short* __restrict__ Ekb) {
    const int t = threadIdx.x;
    for (int i = t; i < 1152; i += 256) {
        int r = i >> 3, c8 = (i & 7) * 8;
        uint4 oq = {0, 0, 0, 0}, ok = {0, 0, 0, 0};
        if (r < NREL) {
            float4 a = *(const float4*)&Eq[r * 64 + c8];
            float4 b = *(const float4*)&Eq[r * 64 + c8 + 4];
            oq.x = pack2(a.x, a.y); oq.y = pack2(a.z, a.w);
            oq.z = pack2(b.x, b.y); oq.w = pack2(b.z, b.w);
            float4 c = *(const float4*)&Ek[r * 64 + c8];
            float4 d = *(const float4*)&Ek[r * 64 + c8 + 4];
            ok.x = pack2(c.x, c.y); ok.y = pack2(c.z, c.w);
            ok.z = pack2(d.x, d.y); ok.w = pack2(d.z, d.w);
        }
        ((uint4*)Eqb)[i] = oq;
        ((uint4*)Ekb)[i] = ok;
    }
}

// ---------------- ee[r] = dot(Eq[r], Ek[r])  (f32)
__global__ void ee_k(const float* __restrict__ Eq, const float* __restrict__ Ek,
                     float* __restrict__ ee) {
    int r = threadIdx.x;
    if (r < NREL) {
        float s = 0.f;
        for (int d = 0; d < HD; d++) s += Eq[r * HD + d] * Ek[r * HD + d];
        ee[r] = s;
    }
}

// ---------------- fused projection (m97 structure): [8192x3072] = xb @ W
__global__ __launch_bounds__(256) void proj_mfma(const unsigned short* __restrict__ xb,
                                                 const unsigned short* __restrict__ WbT,
                                                 unsigned short* __restrict__ Qb,
                                                 unsigned short* __restrict__ Kb,
                                                 unsigned short* __restrict__ Vb) {
    __shared__ uint4 smem[2176];
    const int t = threadIdx.x;
    const int bm = blockIdx.x & 63;
    const int bn = blockIdx.x >> 6;
    const int m0 = bm * 128;
    const int n0g = bn * 128;
    const int w = t >> 6, lane = t & 63, ln = lane & 15, kg = lane >> 4;
    const int wm = w >> 1, wn = w & 1;
    const int lrow = lane >> 3;
    const int lcol = lane & 7;

    f32x4 acc[4][4];
#pragma unroll
    for (int i = 0; i < 4; i++)
#pragma unroll
        for (int j = 0; j < 4; j++) acc[i][j] = (f32x4){0.f, 0.f, 0.f, 0.f};

    const uint4* gA[4]; const uint4* gB[4]; uint4* lA[4]; uint4* lB[4];
#pragma unroll
    for (int j = 0; j < 4; j++) {
        const int seg = w * 4 + j;
        gA[j] = (const uint4*)xb  + (size_t)(m0  + seg * 8 + lrow) * 128 + lcol;
        gB[j] = (const uint4*)WbT + (size_t)(n0g + seg * 8 + lrow) * 128 + lcol;
        lA[j] = smem + seg * 64;
        lB[j] = smem + 1024 + seg * 64;
    }

    for (int kt = 0; kt < 16; ++kt) {
        __syncthreads();
#pragma unroll
        for (int j = 0; j < 4; j++) {
            gld_lds16(gA[j] + kt * 8, lA[j]);
            gld_lds16(gB[j] + kt * 8, lB[j]);
        }
        __syncthreads();
#pragma unroll
        for (int ks = 0; ks < 2; ks++) {
            bf16x8 af[4], bfr[4];
            const int ch = ks * 4 + kg;
#pragma unroll
            for (int i = 0; i < 4; i++) af[i]  = *(const bf16x8*)(smem + (wm * 64 + i * 16 + ln) * 8 + ch);
#pragma unroll
            for (int j = 0; j < 4; j++) bfr[j] = *(const bf16x8*)(smem + 1024 + (wn * 64 + j * 16 + ln) * 8 + ch);
#pragma unroll
            for (int i = 0; i < 4; i++)
#pragma unroll
                for (int j = 0; j < 4; j++)
                    acc[i][j] = __builtin_amdgcn_mfma_f32_16x16x32_bf16(af[i], bfr[j], acc[i][j], 0, 0, 0);
        }
    }
    __syncthreads();
    short (*cs)[136] = (short(*)[136])smem;
#pragma unroll
    for (int i = 0; i < 4; i++)
#pragma unroll
        for (int j = 0; j < 4; j++)
#pragma unroll
            for (int reg = 0; reg < 4; reg++)
                cs[wm * 64 + i * 16 + kg * 4 + reg][wn * 64 + j * 16 + ln] = (short)f2bf(acc[i][j][reg]);
    __syncthreads();
    const int which = n0g >> 10;
    unsigned short* outp = which == 0 ? Qb : (which == 1 ? Kb : Vb);
    const int ncol0 = n0g & 1023;
#pragma unroll
    for (int j = 0; j < 8; j++) {
        int id = j * 256 + t;
        int r = id >> 4, c = id & 15;
        *((uint4*)(outp + (size_t)(m0 + r) * 1024 + ncol0) + c) = *((const uint4*)&cs[r][0] + c);
    }
}

// ---------------- qEe/kEb via MFMA
__global__ __launch_bounds__(256) void qk_e_mfma(const unsigned short* __restrict__ Qb,
                                                 const unsigned short* __restrict__ Kb,
                                                 const unsigned short* __restrict__ Ekb,
                                                 const unsigned short* __restrict__ Eqb,
                                                 const float* __restrict__ ee,
                                                 unsigned short* __restrict__ qEe,
                                                 unsigned short* __restrict__ kEb) {
    __shared__ uint4 lds[3328];
    __shared__ float eeS[136];
    uint4* Qt = lds;
    uint4* Kt = lds + 512;
    uint4* EkS = lds + 1024;
    uint4* EqS = lds + 2176;
    const int t = threadIdx.x, w = t >> 6, lane = t & 63, ln = lane & 15, kg = lane >> 4;
    const int g0 = blockIdx.x * 64;

    {
        int r = t >> 2, cb = (t & 3) * 2;
        const uint4* qg = (const uint4*)Qb + (size_t)(g0 + r) * 8;
        const uint4* kgp = (const uint4*)Kb + (size_t)(g0 + r) * 8;
#pragma unroll
        for (int j = 0; j < 2; j++) {
            int c = cb + j;
            Qt[r * 8 + (c ^ (r & 7))] = qg[c];
            Kt[r * 8 + (c ^ (r & 7))] = kgp[c];
        }
    }
    for (int i = t; i < 1152; i += 256) {
        int r = i >> 3, c = i & 7;
        EkS[r * 8 + (c ^ (r & 7))] = ((const uint4*)Ekb)[i];
        EqS[r * 8 + (c ^ (r & 7))] = ((const uint4*)Eqb)[i];
    }
    if (t < NREL) eeS[t] = ee[t];
    __syncthreads();

    const int lx = ln & 7;
    {
        bf16x8 a0 = *(bf16x8*)&Qt[(w * 16 + ln) * 8 + (kg ^ lx)];
        bf16x8 a1 = *(bf16x8*)&Qt[(w * 16 + ln) * 8 + ((4 + kg) ^ lx)];
        f32x4 acc[9];
#pragma unroll
        for (int j = 0; j < 9; j++) acc[j] = (f32x4){0.f, 0.f, 0.f, 0.f};
#pragma unroll
        for (int j = 0; j < 9; j++) {
            acc[j] = __builtin_amdgcn_mfma_f32_16x16x32_bf16(a0, *(bf16x8*)&EkS[(j * 16 + ln) * 8 + (kg ^ lx)], acc[j], 0, 0, 0);
            acc[j] = __builtin_amdgcn_mfma_f32_16x16x32_bf16(a1, *(bf16x8*)&EkS[(j * 16 + ln) * 8 + ((4 + kg) ^ lx)], acc[j], 0, 0, 0);
        }
#pragma unroll
        for (int j = 0; j < 9; j++) {
            int r = j * 16 + ln;
            if (r <= 128) {
#pragma unroll
                for (int reg = 0; reg < 4; reg++) {
                    int g = g0 + w * 16 + kg * 4 + reg;
                    qEe[(size_t)g * ER + r] = f2bf(acc[j][reg] + eeS[r]);
                }
            }
        }
    }
    {
        bf16x8 a0 = *(bf16x8*)&Kt[(w * 16 + ln) * 8 + (kg ^ lx)];
        bf16x8 a1 = *(bf16x8*)&Kt[(w * 16 + ln) * 8 + ((4 + kg) ^ lx)];
        f32x4 acc[9];
#pragma unroll
        for (int j = 0; j < 9; j++) acc[j] = (f32x4){0.f, 0.f, 0.f, 0.f};
#pragma unroll
        for (int j = 0; j < 9; j++) {
            acc[j] = __builtin_amdgcn_mfma_f32_16x16x32_bf16(a0, *(bf16x8*)&EqS[(j * 16 + ln) * 8 + (kg ^ lx)], acc[j], 0, 0, 0);
            acc[j] = __builtin_amdgcn_mfma_f32_16x16x32_bf16(a1, *(bf16x8*)&EqS[(j * 16 + ln) * 8 + ((4 + kg) ^ lx)], acc[j], 0, 0, 0);
        }
#pragma unroll
        for (int j = 0; j < 9; j++) {
            int r = j * 16 + ln;
            if (r <= 128) {
#pragma unroll
                for (int reg = 0; reg < 4; reg++) {
                    int g = g0 + w * 16 + kg * 4 + reg;
                    kEb[(size_t)g * ER + r] = f2bf(acc[j][reg]);
                }
            }
        }
    }
}

// ---------------- attention: 512 threads / 8 waves; wave pairs split each 32-m tile
// waves w: gq = w&3 (16 l-rows), msub = w>>2 (16-column half); PV/out split by nt-pair
__global__ __launch_bounds__(512) void attn_k(const unsigned short* __restrict__ Q,
                                              const unsigned short* __restrict__ K,
                                              const unsigned short* __restrict__ V,
                                              const unsigned short* __restrict__ qEg,
                                              const unsigned short* __restrict__ kEg,
                                              const float* __restrict__ Ev,
                                              float* __restrict__ out) {
    __shared__ __align__(16) char un[18432];        // Qsb | (Kt,Vtt,kEt) | epilogue EvT
    __shared__ short qEeS[64][ER];                  // 17408
    __shared__ short Pt[8][16][20];                 // 10240
    __shared__ short aRs[4][16][ER];                // 17408
    __shared__ float rsB[2][64];                    // 512
    __shared__ float s0B[2][64];                    // 512
    __shared__ float s128B[2][64];                  // 512
    __shared__ float invs[64];                      // 256  (total 65280)

    short (*Qsb)[64] = (short(*)[64])un;            // 8192 (prologue)
    short (*Kt)[72]  = (short(*)[72])un;            // 4608
    short* Vtt       = (short*)(un + 4608);         // [64 d][40] chunk-swizzled, 5120
    short (*kEt)[ER] = (short(*)[ER])(un + 9728);   // 8704
    short (*EvT)[ER] = (short(*)[ER])un;            // epilogue overlay [64][136]

    const int t = threadIdx.x;
    // supergroup swizzle: 8 same-bh blocks -> same XCD, adjacent in dispatch
    const int g = blockIdx.x;
    const int lt = (g >> 3) & 7;
    const int bh = ((g >> 6) << 3) | (g & 7);
    const int b = bh >> 4, h = bh & 15;
    const int bS = b * SEQ;
    const int l0 = lt * 64;
    const int w = t >> 6;
    const int lane = t & 63;
    const int ln = lane & 15;
    const int kg = lane >> 4;
    const int gq = w & 3;           // l-row group
    const int msub = w >> 2;        // m-half of tile
    const int ntb = msub * 2;       // this wave's output d-pair
    const int l0w = l0 + gq * 16;

    // ---- startup staging
    {
        int r = t >> 3, c8 = (t & 7) * 8;
        *(uint4*)&Qsb[r][c8] = *(const uint4*)&Q[(size_t)(bS + l0 + r) * 1024 + h * 64 + c8];
    }
    for (int i = t; i < 1088; i += 512) {
        int r = i / 17, c = i % 17;
        ((uint4*)&qEeS[r][0])[c] = ((const uint4*)&qEg[(size_t)((bS + l0 + r) * NH + h) * ER])[c];
    }
    for (int i = t; i < 4352; i += 512) ((unsigned*)aRs)[i] = 0u;
    __syncthreads();

    bf16x8 qf0 = *(bf16x8*)&Qsb[gq * 16 + ln][kg * 8];
    bf16x8 qf1 = *(bf16x8*)&Qsb[gq * 16 + ln][32 + kg * 8];

    // ---- T14 staging roles: waves 0-3 stage K/V; waves 4-7 stage kE
    const int sr = (t & 255) >> 3;          // 0..31 (K/V m-row)
    const int sc8 = (t & 7) * 8;
    const unsigned short* Kg0 = K + (size_t)(bS + sr) * 1024 + h * 64 + sc8;
    const unsigned short* Vg0 = V + (size_t)(bS + sr) * 1024 + h * 64 + sc8;
    const int u = t & 255;
    const int r0 = u / 17,          c0 = u % 17;
    const int r1 = (u + 256) / 17,  c1 = (u + 256) % 17;
    const int r2 = (u + 512) / 17,  c2 = (u + 512) % 17;   // only u<32
    const unsigned short* kE0 = kEg + ((size_t)(bS + r0) * NH + h) * ER;
    const unsigned short* kE1 = kEg + ((size_t)(bS + r1) * NH + h) * ER;
    const unsigned short* kE2 = kEg + ((size_t)(bS + r2) * NH + h) * ER;

    uint4 kv, vv, ke0, ke1, ke2;
    if (w < 4) {
        kv = *(const uint4*)(Kg0);
        vv = *(const uint4*)(Vg0);
    } else {
        ke0 = ((const uint4*)kE0)[c0];
        ke1 = ((const uint4*)kE1)[c1];
        if (u < 32) ke2 = ((const uint4*)kE2)[c2];
    }

    f32x4 of[2];
    of[0] = (f32x4){0.f, 0.f, 0.f, 0.f};
    of[1] = (f32x4){0.f, 0.f, 0.f, 0.f};
    float rs[4]   = {0.f, 0.f, 0.f, 0.f};
    float s0[4]   = {0.f, 0.f, 0.f, 0.f};
    float s128[4] = {0.f, 0.f, 0.f, 0.f};

    const int vkey = (t & 7) & 3;
    const int mloc = msub * 16 + ln;        // this wave-lane's m within tile

    for (int mt = 0; mt < 16; mt++) {
        const int m0 = mt * 32;
        __syncthreads();                // A: prior tile's readers done
        if (w < 4) {
            *(uint4*)&Kt[sr][sc8] = kv;
            const short* vs = (const short*)&vv;
#pragma unroll
            for (int j = 0; j < 8; j++) {
                const int d = sc8 + j;
                Vtt[d * 40 + ((((sr >> 3) ^ vkey)) << 3) + (sr & 7)] = vs[j];
            }
        } else {
            ((uint4*)&kEt[r0][0])[c0] = ke0;
            ((uint4*)&kEt[r1][0])[c1] = ke1;
            if (u < 32) ((uint4*)&kEt[r2][0])[c2] = ke2;
        }
        if (mt < 15) {
            const size_t koff = (size_t)(mt + 1) * 32 * 1024;
            const size_t eoff = (size_t)(mt + 1) * 32 * NH * ER;
            if (w < 4) {
                kv = *(const uint4*)(Kg0 + koff);
                vv = *(const uint4*)(Vg0 + koff);
            } else {
                ke0 = ((const uint4*)(kE0 + eoff))[c0];
                ke1 = ((const uint4*)(kE1 + eoff))[c1];
                if (u < 32) ke2 = ((const uint4*)(kE2 + eoff))[c2];
            }
        }
        __syncthreads();                // B: staged tile visible

        // ---- QK^T (this wave's 16 m-cols) + bias + exp
        const int m = m0 + mloc;
        int rr[4]; float qe[4], kev[4];
#pragma unroll
        for (int reg = 0; reg < 4; reg++) {
            const int lr = gq * 16 + kg * 4 + reg;
            const int dlt = (l0 + lr) - m;
            rr[reg] = min(max(dlt, -64), 64) + 64;       // med3
            qe[reg]  = bf2f((unsigned short)qEeS[lr][rr[reg]]);
            kev[reg] = bf2f((unsigned short)kEt[mloc][rr[reg]]);
        }
        f32x4 acc = (f32x4){0.f, 0.f, 0.f, 0.f};
        acc = __builtin_amdgcn_mfma_f32_16x16x32_bf16(qf0, *(bf16x8*)&Kt[mloc][kg * 8], acc, 0, 0, 0);
        acc = __builtin_amdgcn_mfma_f32_16x16x32_bf16(qf1, *(bf16x8*)&Kt[mloc][32 + kg * 8], acc, 0, 0, 0);
#pragma unroll
        for (int reg = 0; reg < 4; reg++) {
            const int lr = kg * 4 + reg;
            const int dlt = (l0w + lr) - m;
            float p = __expf((acc[reg] + qe[reg] + kev[reg]) * SCALE);
            rs[reg] += p;
            if (dlt >= 64)       s128[reg] += p;
            else if (dlt <= -64) s0[reg]   += p;
            else                 aRs[gq][lr][rr[reg]] = (short)f2bf(p);  // unique cell
            Pt[w][lr][ln] = (short)f2bf(p);
        }
        __syncthreads();                // C: merged P visible across wave pair

        // ---- PV: this wave's nt-pair, full K=32 from merged Pt
        bf16x8 pf = *(bf16x8*)&Pt[gq + ((kg >> 1) << 2)][ln][(kg & 1) * 8];
#pragma unroll
        for (int i = 0; i < 2; i++) {
            const int d = (ntb + i) * 16 + ln;
            const bf16x8 vf = *(const bf16x8*)&Vtt[d * 40 + ((kg ^ ((d >> 3) & 3)) << 3)];
            of[i] = __builtin_amdgcn_mfma_f32_16x16x32_bf16(pf, vf, of[i], 0, 0, 0);
        }
    }

    __syncthreads();                    // un free from here
    // ---- wave-local row reductions (16 lanes share a row)
#pragma unroll
    for (int reg = 0; reg < 4; reg++) {
        for (int off = 1; off <= 8; off <<= 1) {
            rs[reg]   += __shfl_xor(rs[reg], off);
            s0[reg]   += __shfl_xor(s0[reg], off);
            s128[reg] += __shfl_xor(s128[reg], off);
        }
    }
    if (ln == 0) {
#pragma unroll
        for (int reg = 0; reg < 4; reg++) {
            const int row = gq * 16 + kg * 4 + reg;
            rsB[msub][row]   = rs[reg];
            s0B[msub][row]   = s0[reg];
            s128B[msub][row] = s128[reg];
        }
    }
    __syncthreads();
    // merged sums -> inv (all waves); edges+invs by waves 0-3; EvT by waves 4-7
    float inv[4], a128[4];
#pragma unroll
    for (int reg = 0; reg < 4; reg++) {
        const int row = gq * 16 + kg * 4 + reg;
        const float rt = rsB[0][row] + rsB[1][row];
        inv[reg] = 1.0f / rt;
        a128[reg] = (s128B[0][row] + s128B[1][row]) * inv[reg];
    }
    if (w < 4) {
        if (ln == 0) {
#pragma unroll
            for (int reg = 0; reg < 4; reg++) {
                const int row = gq * 16 + kg * 4 + reg;
                aRs[gq][kg * 4 + reg][0] = (short)f2bf((s0B[0][row] + s0B[1][row]) * inv[reg]);
                invs[row] = inv[reg];
            }
        }
    } else {
        for (int i = t - 256; i < 8256; i += 256) {      // 129*64
            int r = i >> 6, d = i & 63;
            EvT[d][r] = (short)f2bf(Ev[i]);
        }
    }
    __syncthreads();
    // normalize band cols 1..127 (waves 0-3)
    if (w < 4) {
        const int row = lane >> 2;
        const float sc = invs[gq * 16 + row];
#pragma unroll
        for (int kk = 0; kk < 32; kk++) {
            int c = (lane & 3) * 32 + kk;
            if (c >= 1) aRs[gq][row][c] = (short)f2bf(bf2f((unsigned short)aRs[gq][row][c]) * sc);
        }
    }
#pragma unroll
    for (int i = 0; i < 2; i++)
#pragma unroll
        for (int reg = 0; reg < 4; reg++) of[i][reg] *= inv[reg];
    __syncthreads();

    // ---- fused rel_av (this wave's nt-pair) + store
    f32x4 o2[2];
    o2[0] = (f32x4){0.f, 0.f, 0.f, 0.f};
    o2[1] = (f32x4){0.f, 0.f, 0.f, 0.f};
#pragma unroll
    for (int i = 0; i < 2; i++)
#pragma unroll
        for (int ks = 0; ks < 4; ks++)
            o2[i] = __builtin_amdgcn_mfma_f32_16x16x32_bf16(*(bf16x8*)&aRs[gq][ln][ks * 32 + kg * 8],
                                                            *(bf16x8*)&EvT[(ntb + i) * 16 + ln][ks * 32 + kg * 8],
                                                            o2[i], 0, 0, 0);
#pragma unroll
    for (int i = 0; i < 2; i++) {
        const int nt = ntb + i;
        const float e128 = bf2f((unsigned short)EvT[nt * 16 + ln][128]);
#pragma unroll
        for (int reg = 0; reg < 4; reg++) {
            const int lr = kg * 4 + reg;
            out[(size_t)(bS + l0w + lr) * 1024 + h * 64 + nt * 16 + ln] =
                of[i][reg] + o2[i][reg] + a128[reg] * e128;
        }
    }
}

extern "C" void kernel_launch(void* const* d_in, const int* in_sizes, int n_in,
                              void* d_out, int out_size, void* d_ws, size_t ws_size,
                              hipStream_t stream) {
    const float* x  = (const float*)d_in[0];
    const float* Wq = (const float*)d_in[1];
    const float* Wk = (const float*)d_in[2];
    const float* Wv = (const float*)d_in[3];
    const float* Eq = (const float*)d_in[4];
    const float* Ek = (const float*)d_in[5];
    const float* Ev = (const float*)d_in[6];
    float* out = (float*)d_out;
    char* ws = (char*)d_ws;

    unsigned short* Qb  = (unsigned short*)(ws);                    // 16,777,216
    unsigned short* Kb  = (unsigned short*)(ws + 16777216ull);
    unsigned short* Vb  = (unsigned short*)(ws + 33554432ull);
    unsigned short* xb  = (unsigned short*)(ws + 50331648ull);      // 16,777,216
    unsigned short* WbT = (unsigned short*)(ws + 67108864ull);      // 6,291,456
    unsigned short* Ekb = (unsigned short*)(ws + 73400320ull);      // 18,432
    unsigned short* Eqb = (unsigned short*)(ws + 73418752ull);      // 18,432
    float*          ee  = (float*)(ws + 73437184ull);               // 576
    unsigned short* qEe = (unsigned short*)(ws + 73437760ull);      // 35,651,584
    unsigned short* kEb = (unsigned short*)(ws + 109089344ull);     // 35,651,584 (~144.7 MB)

    conv_x<<<4096, 256, 0, stream>>>(x, xb);
    conv_w<<<768, 256, 0, stream>>>(Wq, Wk, Wv, WbT);
    conv_e<<<1, 256, 0, stream>>>(Eq, Ek, Eqb, Ekb);
    ee_k<<<1, 256, 0, stream>>>(Eq, Ek, ee);
    proj_mfma<<<1536, 256, 0, stream>>>(xb, WbT, Qb, Kb, Vb);
    qk_e_mfma<<<2048, 256, 0, stream>>>(Qb, Kb, Ekb, Eqb, ee, qEe, kEb);
    attn_k<<<2048, 512, 0, stream>>>(Qb, Kb, Vb, qEe, kEb, Ev, out);
}